// Round 1
// 1317.072 us; speedup vs baseline: 1.0209x; 1.0209x over previous
//
#include <hip/hip_runtime.h>
#include <hip/hip_bf16.h>

constexpr int kB  = 8;
constexpr int kC  = 256;
constexpr int kCq = 32;
constexpr int kH  = 96;
constexpr int kW  = 96;
constexpr int kP  = kH * kW;      // 9216

using bf16x8 = __attribute__((ext_vector_type(8))) short;
using f32x4  = __attribute__((ext_vector_type(4))) float;

// ---------------------------------------------------------------------------
// Kernel W1: convert Wq+Wk -> Wqkb [64][256] bf16, Wv -> Wvb [256][256] bf16.
// grid 320 x 256.
// ---------------------------------------------------------------------------
__global__ __launch_bounds__(256) void w_convert(
    const float* __restrict__ Wq, const float* __restrict__ Wk,
    const float* __restrict__ Wv,
    __hip_bfloat16* __restrict__ Wqkb, __hip_bfloat16* __restrict__ Wvb)
{
    const int i = blockIdx.x * 256 + threadIdx.x;
    if (i < 8192)       Wqkb[i] = __float2bfloat16(Wq[i]);
    else if (i < 16384) Wqkb[i] = __float2bfloat16(Wk[i - 8192]);
    else                Wvb[i - 16384] = __float2bfloat16(Wv[i - 16384]);
}

// ---------------------------------------------------------------------------
// Kernel A: q/k/v projection GEMM via bf16 MFMA, no LDS.  (unchanged)
// ---------------------------------------------------------------------------
__global__ __launch_bounds__(256) void qkv_mfma(
    const float* __restrict__ in_qk, const float* __restrict__ in_v,
    const __hip_bfloat16* __restrict__ Wqkb, const __hip_bfloat16* __restrict__ Wvb,
    const float* __restrict__ bq, const float* __restrict__ bk,
    const float* __restrict__ bv,
    float* __restrict__ Q, float* __restrict__ K, float* __restrict__ V)
{
    const int b = blockIdx.y;
    const int t = threadIdx.x;
    const int wv = t >> 6, l = t & 63;
    const int n = l & 15, q = l >> 4;            // n = pixel col, q = quad
    const int p = blockIdx.x * 64 + wv * 16 + n; // this lane's pixel
    const size_t bP = (size_t)b * kP;

    const float* __restrict__ xq = in_qk + (size_t)b * kC * kP + p;
    const float* __restrict__ xv = in_v  + (size_t)b * kC * kP + p;

    f32x4 acc[20];
#pragma unroll
    for (int i = 0; i < 20; i++) acc[i] = (f32x4)0.f;

    for (int kc = 0; kc < 8; kc++) {
        const int c0 = kc * 32 + q * 8;          // this lane's k-slice base
        float fq[8], fv[8];
#pragma unroll
        for (int j = 0; j < 8; j++) fq[j] = xq[(size_t)(c0 + j) * kP];
#pragma unroll
        for (int j = 0; j < 8; j++) fv[j] = xv[(size_t)(c0 + j) * kP];
        union { bf16x8 v; __hip_bfloat16 h[8]; } bfq, bfv;
#pragma unroll
        for (int j = 0; j < 8; j++) bfq.h[j] = __float2bfloat16(fq[j]);
#pragma unroll
        for (int j = 0; j < 8; j++) bfv.h[j] = __float2bfloat16(fv[j]);

#pragma unroll
        for (int mt = 0; mt < 4; mt++) {
            bf16x8 a = *(const bf16x8*)(Wqkb + ((mt * 16 + n) << 8) + c0);
            acc[mt] = __builtin_amdgcn_mfma_f32_16x16x32_bf16(a, bfq.v, acc[mt], 0, 0, 0);
        }
#pragma unroll
        for (int mt = 0; mt < 16; mt++) {
            bf16x8 a = *(const bf16x8*)(Wvb + ((mt * 16 + n) << 8) + c0);
            acc[4 + mt] = __builtin_amdgcn_mfma_f32_16x16x32_bf16(a, bfv.v, acc[4 + mt], 0, 0, 0);
        }
    }

    float* __restrict__ Qp = Q + (bP + p) * kCq;
    float* __restrict__ Kp = K + (bP + p) * kCq;
    float* __restrict__ Vp = V + (bP + p) * kC;
#pragma unroll
    for (int mt = 0; mt < 2; mt++) {
        float4 bias = *(const float4*)&bq[mt * 16 + q * 4];
        float4 r = { acc[mt][0] + bias.x, acc[mt][1] + bias.y,
                     acc[mt][2] + bias.z, acc[mt][3] + bias.w };
        *(float4*)&Qp[mt * 16 + q * 4] = r;
    }
#pragma unroll
    for (int mt = 2; mt < 4; mt++) {
        float4 bias = *(const float4*)&bk[(mt - 2) * 16 + q * 4];
        float4 r = { acc[mt][0] + bias.x, acc[mt][1] + bias.y,
                     acc[mt][2] + bias.z, acc[mt][3] + bias.w };
        *(float4*)&Kp[(mt - 2) * 16 + q * 4] = r;
    }
#pragma unroll
    for (int mt = 0; mt < 16; mt++) {
        float4 bias = *(const float4*)&bv[mt * 16 + q * 4];
        float4 r = { acc[4 + mt][0] + bias.x, acc[4 + mt][1] + bias.y,
                     acc[4 + mt][2] + bias.z, acc[4 + mt][3] + bias.w };
        *(float4*)&Vp[mt * 16 + q * 4] = r;
    }
}

// ---------------------------------------------------------------------------
// Kernel B: pass1 (one stream). grid (W/32, H, B), block 256.
// v2: online softmax over eH (scores never stored), only eW raw scores kept
// in LDS; outW re-tiled as (4ch x 8px)/thread so att LDS reads drop 768->192
// per thread and V loads become float4; residual staged pixel-major for
// float4 epilogue reads + ushort4 Zb stores.  LDS 51.2 KB -> 3 blocks/CU.
// ---------------------------------------------------------------------------
__global__ __launch_bounds__(256) void cc_pass1(
    const float* __restrict__ Q, const float* __restrict__ K, const float* __restrict__ V,
    const float* __restrict__ res_in, const float* __restrict__ gamma_p,
    __hip_bfloat16* __restrict__ Zb, float* __restrict__ Sm, float* __restrict__ Si,
    int s_off)
{
    __shared__ __align__(16) float qs[32][36];    // Q tile [px][c]   (4.6 KB)
    __shared__ __align__(16) float scw[32][104];  // eW scores/att    (13.3 KB)
    __shared__ __align__(16) float rs[32][260];   // residual [px][c] (33.3 KB)
    const int wt = blockIdx.x, h = blockIdx.y, b = blockIdx.z;
    const int w0 = wt * 32;
    const int t = threadIdx.x;
    const size_t bP = (size_t)b * kP;

    // stage Q tile (coalesced 128B runs)
    for (int l = t; l < 32 * 32; l += 256) {
        int i = l >> 5, c = l & 31;
        qs[i][c] = Q[(bP + (size_t)h * kW + w0 + i) * kCq + c];
    }
    // stage residual tile, pixel-major: rs[px][c]
    const float* __restrict__ res = res_in + (size_t)b * kC * kP + (size_t)h * kW + w0;
    {
        const int f4 = t & 7;
        int c2 = t >> 3;
#pragma unroll
        for (int it = 0; it < 8; it++, c2 += 32) {
            float4 v = *(const float4*)&res[(size_t)c2 * kP + f4 * 4];
            rs[f4 * 4 + 0][c2] = v.x;
            rs[f4 * 4 + 1][c2] = v.y;
            rs[f4 * 4 + 2][c2] = v.z;
            rs[f4 * 4 + 3][c2] = v.w;
        }
    }
    __syncthreads();

    // ---- scores + online softmax: thread = (pi = t>>3, sub = t&7) ----
    {
        const int pi = t >> 3, sub = t & 7;
        float qr[32];
#pragma unroll
        for (int c4 = 0; c4 < 8; c4++) {
            float4 q4 = *(const float4*)&qs[pi][c4 * 4];
            qr[c4 * 4 + 0] = q4.x; qr[c4 * 4 + 1] = q4.y;
            qr[c4 * 4 + 2] = q4.z; qr[c4 * 4 + 3] = q4.w;
        }
        float m = -3.0e38f, s = 0.f;
        const float4* __restrict__ KH =
            (const float4*)(K + (bP + (size_t)h * kW) * kCq);
        for (int k = 0; k < 12; k++) {
            const int jj = sub + 8 * k;
            // eH score: K row (jj, w0+pi); diagonal masked (== skip)
            if (jj != h) {
                const float4* k4 =
                    (const float4*)(K + (bP + (size_t)jj * kW + w0 + pi) * kCq);
                float d0 = 0.f, d1 = 0.f;
#pragma unroll
                for (int c4 = 0; c4 < 8; c4 += 2) {
                    float4 ka = k4[c4], kb = k4[c4 + 1];
                    d0 += ka.x * qr[c4 * 4 + 0] + ka.y * qr[c4 * 4 + 1]
                        + ka.z * qr[c4 * 4 + 2] + ka.w * qr[c4 * 4 + 3];
                    d1 += kb.x * qr[c4 * 4 + 4] + kb.y * qr[c4 * 4 + 5]
                        + kb.z * qr[c4 * 4 + 6] + kb.w * qr[c4 * 4 + 7];
                }
                float dot = d0 + d1;
                float mn = fmaxf(m, dot);
                s = s * __expf(m - mn) + __expf(dot - mn);
                m = mn;
            }
            // eW score: K row (h, jj); store raw dot for reuse in outW
            {
                const float4* k4 = KH + (size_t)jj * 8;
                float d0 = 0.f, d1 = 0.f;
#pragma unroll
                for (int c4 = 0; c4 < 8; c4 += 2) {
                    float4 ka = k4[c4], kb = k4[c4 + 1];
                    d0 += ka.x * qr[c4 * 4 + 0] + ka.y * qr[c4 * 4 + 1]
                        + ka.z * qr[c4 * 4 + 2] + ka.w * qr[c4 * 4 + 3];
                    d1 += kb.x * qr[c4 * 4 + 4] + kb.y * qr[c4 * 4 + 5]
                        + kb.z * qr[c4 * 4 + 6] + kb.w * qr[c4 * 4 + 7];
                }
                float dot = d0 + d1;
                scw[pi][jj] = dot;
                float mn = fmaxf(m, dot);
                s = s * __expf(m - mn) + __expf(dot - mn);
                m = mn;
            }
        }
        // combine (m, s) across the 8 sub-threads of this pixel
#pragma unroll
        for (int k = 1; k < 8; k <<= 1) {
            float mo = __shfl_xor(m, k, 8);
            float so = __shfl_xor(s, k, 8);
            float mn = fmaxf(m, mo);
            s = s * __expf(m - mn) + so * __expf(mo - mn);
            m = mn;
        }
        const float inv = 1.0f / s;
        if (sub == 0) {
            Sm[bP + (size_t)h * kW + w0 + pi] = m;
            Si[bP + (size_t)h * kW + w0 + pi] = inv;
        }
        // normalize eW -> attention weights (in place, same-thread elements)
#pragma unroll
        for (int k = 0; k < 12; k++) {
            const int jj = sub + 8 * k;
            scw[pi][jj] = __expf(scw[pi][jj] - m) * inv;
        }
    }
    __syncthreads();

    // ---- outW: thread = (cg = t&63 -> 4 channels, pg = t>>6 -> 8 pixels) ----
    const int cg = t & 63, pg = t >> 6;
    const float* __restrict__ vrow = V + (bP + (size_t)h * kW) * kC + 4 * cg;
    float4 acc[8];
#pragma unroll
    for (int px = 0; px < 8; px++) acc[px] = make_float4(0.f, 0.f, 0.f, 0.f);
    for (int j = 0; j < 96; j += 4) {
        float4 v0 = *(const float4*)&vrow[(size_t)(j + 0) * kC];
        float4 v1 = *(const float4*)&vrow[(size_t)(j + 1) * kC];
        float4 v2 = *(const float4*)&vrow[(size_t)(j + 2) * kC];
        float4 v3 = *(const float4*)&vrow[(size_t)(j + 3) * kC];
#pragma unroll
        for (int px = 0; px < 8; px++) {
            float4 a = *(const float4*)&scw[8 * pg + px][j];   // wave-uniform
            acc[px].x += a.x * v0.x + a.y * v1.x + a.z * v2.x + a.w * v3.x;
            acc[px].y += a.x * v0.y + a.y * v1.y + a.z * v2.y + a.w * v3.y;
            acc[px].z += a.x * v0.z + a.y * v1.z + a.z * v2.z + a.w * v3.z;
            acc[px].w += a.x * v0.w + a.y * v1.w + a.z * v2.w + a.w * v3.w;
        }
    }

    // ---- epilogue: gamma*outW + residual -> bf16, coalesced ushort4 ----
    const float gamma = gamma_p[0];
#pragma unroll
    for (int px = 0; px < 8; px++) {
        float4 rr = *(const float4*)&rs[8 * pg + px][4 * cg];
        union { ushort4 u; __hip_bfloat16 hh[4]; } z;
        z.hh[0] = __float2bfloat16(gamma * acc[px].x + rr.x);
        z.hh[1] = __float2bfloat16(gamma * acc[px].y + rr.y);
        z.hh[2] = __float2bfloat16(gamma * acc[px].z + rr.z);
        z.hh[3] = __float2bfloat16(gamma * acc[px].w + rr.w);
        *(ushort4*)&Zb[(bP + (size_t)h * kW + w0 + 8 * pg + px) * 512
                       + s_off + 4 * cg] = z.u;
    }
}

// ---------------------------------------------------------------------------
// Kernel C: pass2 (one stream). grid (H/32, W, B), block 256.
// v2: q row hoisted to registers; outH re-tiled as (4ch x 8px)/thread
// (att LDS reads 768 -> 192 per thread); Zb RMW via ushort4. LDS 31.7 KB.
// ---------------------------------------------------------------------------
__global__ __launch_bounds__(256) void cc_pass2(
    const float* __restrict__ Q, const float* __restrict__ K, const float* __restrict__ V,
    const float* __restrict__ gamma_p,
    __hip_bfloat16* __restrict__ Zb, const float* __restrict__ Sm, const float* __restrict__ Si,
    int s_off)
{
    __shared__ __align__(16) float qs2[32][36];
    __shared__ __align__(16) float ks2[96][36];
    __shared__ __align__(16) float ah[32][104];
    const int ht = blockIdx.x, w = blockIdx.y, b = blockIdx.z;
    const int h0 = ht * 32;
    const int t = threadIdx.x;
    const size_t bP = (size_t)b * kP;

    for (int l = t; l < 32 * 32; l += 256) {
        int i = l >> 5, c = l & 31;
        qs2[i][c] = Q[(bP + (size_t)(h0 + i) * kW + w) * kCq + c];
    }
    for (int l = t; l < 96 * 32; l += 256) {
        int j = l >> 5, c = l & 31;
        ks2[j][c] = K[(bP + (size_t)j * kW + w) * kCq + c];
    }
    __syncthreads();

    {   // recompute eH scores + softmax weights via stored stats
        const int i = t & 31, jg = t >> 5;
        float qr[32];
#pragma unroll
        for (int c4 = 0; c4 < 8; c4++) {
            float4 q4 = *(const float4*)&qs2[i][c4 * 4];
            qr[c4 * 4 + 0] = q4.x; qr[c4 * 4 + 1] = q4.y;
            qr[c4 * 4 + 2] = q4.z; qr[c4 * 4 + 3] = q4.w;
        }
        const float mi = Sm[bP + (size_t)(h0 + i) * kW + w];
        const float ii = Si[bP + (size_t)(h0 + i) * kW + w];
        for (int j = jg; j < 96; j += 8) {
            float d0 = 0.f, d1 = 0.f;
#pragma unroll
            for (int c4 = 0; c4 < 8; c4 += 2) {
                float4 ka = *(const float4*)&ks2[j][c4 * 4];
                float4 kb = *(const float4*)&ks2[j][c4 * 4 + 4];
                d0 += ka.x * qr[c4 * 4 + 0] + ka.y * qr[c4 * 4 + 1]
                    + ka.z * qr[c4 * 4 + 2] + ka.w * qr[c4 * 4 + 3];
                d1 += kb.x * qr[c4 * 4 + 4] + kb.y * qr[c4 * 4 + 5]
                    + kb.z * qr[c4 * 4 + 6] + kb.w * qr[c4 * 4 + 7];
            }
            float dot = d0 + d1;
            ah[i][j] = (j == h0 + i) ? 0.f : __expf(dot - mi) * ii;
        }
    }
    __syncthreads();

    // ---- outH: thread = (cg -> 4 channels, pg -> 8 pixels) ----
    const int cg = t & 63, pg = t >> 6;
    const float* __restrict__ vcol = V + (bP + (size_t)w) * kC + 4 * cg;
    float4 acc[8];
#pragma unroll
    for (int px = 0; px < 8; px++) acc[px] = make_float4(0.f, 0.f, 0.f, 0.f);
    for (int j = 0; j < 96; j += 4) {
        float4 v0 = *(const float4*)&vcol[(size_t)(j + 0) * (kW * kC)];
        float4 v1 = *(const float4*)&vcol[(size_t)(j + 1) * (kW * kC)];
        float4 v2 = *(const float4*)&vcol[(size_t)(j + 2) * (kW * kC)];
        float4 v3 = *(const float4*)&vcol[(size_t)(j + 3) * (kW * kC)];
#pragma unroll
        for (int px = 0; px < 8; px++) {
            float4 a = *(const float4*)&ah[8 * pg + px][j];    // wave-uniform
            acc[px].x += a.x * v0.x + a.y * v1.x + a.z * v2.x + a.w * v3.x;
            acc[px].y += a.x * v0.y + a.y * v1.y + a.z * v2.y + a.w * v3.y;
            acc[px].z += a.x * v0.z + a.y * v1.z + a.z * v2.z + a.w * v3.z;
            acc[px].w += a.x * v0.w + a.y * v1.w + a.z * v2.w + a.w * v3.w;
        }
    }

    const float gamma = gamma_p[0];
#pragma unroll
    for (int px = 0; px < 8; px++) {
        size_t zi = (bP + (size_t)(h0 + 8 * pg + px) * kW + w) * 512
                    + s_off + 4 * cg;
        union { ushort4 u; __hip_bfloat16 hh[4]; } zo, zn;
        zo.u = *(const ushort4*)&Zb[zi];
        zn.hh[0] = __float2bfloat16(__bfloat162float(zo.hh[0]) + gamma * acc[px].x);
        zn.hh[1] = __float2bfloat16(__bfloat162float(zo.hh[1]) + gamma * acc[px].y);
        zn.hh[2] = __float2bfloat16(__bfloat162float(zo.hh[2]) + gamma * acc[px].z);
        zn.hh[3] = __float2bfloat16(__bfloat162float(zo.hh[3]) + gamma * acc[px].w);
        *(ushort4*)&Zb[zi] = zn.u;
    }
}

// ---------------------------------------------------------------------------
// Kernel W2: convert Wp [256][512] fp32 -> bf16 (into dead Q region of ws).
// ---------------------------------------------------------------------------
__global__ __launch_bounds__(256) void wp_convert(
    const float* __restrict__ Wp, __hip_bfloat16* __restrict__ Wpb)
{
    const int i = blockIdx.x * 256 + threadIdx.x;
    Wpb[i] = __float2bfloat16(Wp[i]);
}

// ---------------------------------------------------------------------------
// Kernel D: fused depthwise 3x3 + pointwise 512->256 (bf16 MFMA) + leaky relu.
// (unchanged)
// ---------------------------------------------------------------------------
__global__ __launch_bounds__(256) void dwpw(
    const __hip_bfloat16* __restrict__ Zb,
    const float* __restrict__ Wdw, const float* __restrict__ bd,
    const __hip_bfloat16* __restrict__ Wpb, const float* __restrict__ bp,
    float* __restrict__ out)
{
    __shared__ __align__(16) char smem[33792];
    __hip_bfloat16 (*zs)[520] = (__hip_bfloat16 (*)[520])smem;

    const int wt = blockIdx.x, h = blockIdx.y, b = blockIdx.z;
    const int w0 = wt * 32;
    const int t = threadIdx.x;
    const size_t bP = (size_t)b * kP;

    {
        float wd0[9], wd1[9];
#pragma unroll
        for (int k = 0; k < 9; k++) {
            wd0[k] = Wdw[(size_t)(2 * t) * 9 + k];
            wd1[k] = Wdw[(size_t)(2 * t + 1) * 9 + k];
        }
        const float b0 = bd[2 * t], b1 = bd[2 * t + 1];
        const __hip_bfloat162* __restrict__ Zp =
            (const __hip_bfloat162*)Zb + bP * 256 + t;
        const bool rvm = (h > 0), rvp = (h < kH - 1);

#pragma unroll
        for (int j0 = 0; j0 < 32; j0 += 8) {
            float2 wf[10][3];
#pragma unroll
            for (int col = 0; col < 10; col++) {
                const int ww = w0 + j0 - 1 + col;
                const bool cv = (ww >= 0) && (ww < kW);
#pragma unroll
                for (int r = 0; r < 3; r++) {
                    const bool v = cv && (r == 1 || (r == 0 ? rvm : rvp));
                    __hip_bfloat162 z2;
                    z2.x = __ushort_as_bfloat16(0);
                    z2.y = __ushort_as_bfloat16(0);
                    if (v) z2 = Zp[(size_t)((h + r - 1) * kW + ww) * 256];
                    wf[col][r] = __bfloat1622float2(z2);
                }
            }
#pragma unroll
            for (int j = 0; j < 8; j++) {
                float a0 = b0, a1 = b1;
#pragma unroll
                for (int r = 0; r < 3; r++) {
#pragma unroll
                    for (int dw = 0; dw < 3; dw++) {
                        const float2 z = wf[j + dw][r];
                        const int k = r * 3 + dw;
                        a0 += wd0[k] * z.x;
                        a1 += wd1[k] * z.y;
                    }
                }
                __hip_bfloat162 pz;
                pz.x = __float2bfloat16(a0);
                pz.y = __float2bfloat16(a1);
                ((__hip_bfloat162*)&zs[j0 + j][0])[t] = pz;
            }
        }
    }
    __syncthreads();

    const int l = t & 63, wv = t >> 6;
    const int lo16 = l & 15, q = l >> 4;

    f32x4 acc[2][4];
#pragma unroll
    for (int mt = 0; mt < 2; mt++)
#pragma unroll
        for (int nt = 0; nt < 4; nt++) acc[mt][nt] = (f32x4)0.f;

    const bf16x8* __restrict__ Bb[4];
#pragma unroll
    for (int nt = 0; nt < 4; nt++)
        Bb[nt] = (const bf16x8*)(Wpb + (size_t)(wv * 64 + nt * 16 + lo16) * 512);

    for (int kc = 0; kc < 16; kc++) {
        bf16x8 a0 = *(const bf16x8*)&zs[lo16][kc * 32 + q * 8];
        bf16x8 a1 = *(const bf16x8*)&zs[16 + lo16][kc * 32 + q * 8];
#pragma unroll
        for (int nt = 0; nt < 4; nt++) {
            bf16x8 bf = Bb[nt][kc * 4 + q];
            acc[0][nt] = __builtin_amdgcn_mfma_f32_16x16x32_bf16(a0, bf, acc[0][nt], 0, 0, 0);
            acc[1][nt] = __builtin_amdgcn_mfma_f32_16x16x32_bf16(a1, bf, acc[1][nt], 0, 0, 0);
        }
    }
    __syncthreads();

    float* os = (float*)smem + (size_t)wv * 64 * 33;
#pragma unroll
    for (int nt = 0; nt < 4; nt++) {
        const int ol = nt * 16 + lo16;
        const float bias = bp[wv * 64 + ol];
#pragma unroll
        for (int mt = 0; mt < 2; mt++) {
#pragma unroll
            for (int r = 0; r < 4; r++) {
                float v = acc[mt][nt][r] + bias;
                v = v > 0.f ? v : 0.01f * v;
                os[ol * 33 + mt * 16 + q * 4 + r] = v;
            }
        }
    }
    __syncthreads();
    const int px = l & 31, oh = l >> 5;
    for (int j = 0; j < 32; j++) {
        const int ol = j * 2 + oh;
        out[((size_t)b * 256 + wv * 64 + ol) * kP + (size_t)h * kW + w0 + px] =
            os[ol * 33 + px];
    }
}

// ---------------------------------------------------------------------------
extern "C" void kernel_launch(void* const* d_in, const int* in_sizes, int n_in,
                              void* d_out, int out_size, void* d_ws, size_t ws_size,
                              hipStream_t stream)
{
    const float* x   = (const float*)d_in[0];
    const float* y   = (const float*)d_in[1];
    const float* Wq  = (const float*)d_in[2];
    const float* bq  = (const float*)d_in[3];
    const float* Wk  = (const float*)d_in[4];
    const float* bk  = (const float*)d_in[5];
    const float* Wv  = (const float*)d_in[6];
    const float* bv  = (const float*)d_in[7];
    const float* g1  = (const float*)d_in[8];
    const float* g2  = (const float*)d_in[9];
    const float* Wdw = (const float*)d_in[10];
    const float* bd  = (const float*)d_in[11];
    const float* Wp  = (const float*)d_in[12];
    const float* bp  = (const float*)d_in[13];
    float* out = (float*)d_out;

    // Workspace layout (unchanged):
    //   Zb  : bf16 [8][9216][512]  = 75,497,472 B
    //   Q,K : fp32 [8][9216][32]   =  9,437,184 B each
    //   Sm,Si: fp32 [8][9216]      =    294,912 B each
    // V (fp32) lives in d_out until dwpw. Wqkb/Wvb alias dead Sm region;
    // Wpb reuses the Q region after the last cc_pass2.
    char* wsb = (char*)d_ws;
    __hip_bfloat16* Zb = (__hip_bfloat16*)wsb;
    float* Q  = (float*)(wsb + 75497472);
    float* K  = (float*)(wsb + 75497472 + 9437184);
    float* Sm = (float*)(wsb + 75497472 + 2 * 9437184);
    float* Si = (float*)(wsb + 75497472 + 2 * 9437184 + 294912);
    __hip_bfloat16* Wqkb = (__hip_bfloat16*)Sm;
    __hip_bfloat16* Wvb  = (__hip_bfloat16*)(((char*)Sm) + 32768);
    __hip_bfloat16* Wpb  = (__hip_bfloat16*)(wsb + 75497472);
    float* V  = out;

    // stream 1: q,k from x; v from y; residual x; channels [0,256)
    hipLaunchKernelGGL(w_convert, dim3(320), dim3(256), 0, stream,
                       Wq, Wk, Wv, Wqkb, Wvb);
    hipLaunchKernelGGL(qkv_mfma, dim3(kP / 64, kB), dim3(256), 0, stream,
                       x, y, Wqkb, Wvb, bq, bk, bv, Q, K, V);
    hipLaunchKernelGGL(cc_pass1, dim3(kW / 32, kH, kB), dim3(256), 0, stream,
                       Q, K, V, x, g1, Zb, Sm, Si, 0);
    hipLaunchKernelGGL(cc_pass2, dim3(kH / 32, kW, kB), dim3(256), 0, stream,
                       Q, K, V, g1, Zb, Sm, Si, 0);
    // stream 2: q,k from y; v from x; residual y; channels [256,512)
    hipLaunchKernelGGL(w_convert, dim3(320), dim3(256), 0, stream,
                       Wq, Wk, Wv, Wqkb, Wvb);
    hipLaunchKernelGGL(qkv_mfma, dim3(kP / 64, kB), dim3(256), 0, stream,
                       y, x, Wqkb, Wvb, bq, bk, bv, Q, K, V);
    hipLaunchKernelGGL(cc_pass1, dim3(kW / 32, kH, kB), dim3(256), 0, stream,
                       Q, K, V, y, g2, Zb, Sm, Si, 256);
    hipLaunchKernelGGL(cc_pass2, dim3(kH / 32, kW, kB), dim3(256), 0, stream,
                       Q, K, V, g2, Zb, Sm, Si, 256);
    hipLaunchKernelGGL(wp_convert, dim3(512), dim3(256), 0, stream, Wp, Wpb);
    hipLaunchKernelGGL(dwpw, dim3(kW / 32, kH, kB), dim3(256), 0, stream,
                       Zb, Wdw, bd, Wpb, bp, out);
}

// Round 2
// 977.317 us; speedup vs baseline: 1.3757x; 1.3476x over previous
//
#include <hip/hip_runtime.h>
#include <hip/hip_bf16.h>

constexpr int kB  = 8;
constexpr int kC  = 256;
constexpr int kCq = 32;
constexpr int kH  = 96;
constexpr int kW  = 96;
constexpr int kP  = kH * kW;      // 9216

using bf16x8 = __attribute__((ext_vector_type(8))) short;
using bf16x4 = __attribute__((ext_vector_type(4))) short;
using f32x4  = __attribute__((ext_vector_type(4))) float;

// load 8 bf16 from 8B-aligned LDS as two b64 reads
__device__ inline bf16x8 ld_lds8(const __hip_bfloat16* p) {
    bf16x4 lo = *(const bf16x4*)p;
    bf16x4 hi = *(const bf16x4*)(p + 4);
    return __builtin_shufflevector(lo, hi, 0, 1, 2, 3, 4, 5, 6, 7);
}

// ---------------------------------------------------------------------------
// Kernel W1: convert Wq+Wk -> Wqkb [64][256] bf16, Wv -> Wvb [256][256] bf16.
// ---------------------------------------------------------------------------
__global__ __launch_bounds__(256) void w_convert(
    const float* __restrict__ Wq, const float* __restrict__ Wk,
    const float* __restrict__ Wv,
    __hip_bfloat16* __restrict__ Wqkb, __hip_bfloat16* __restrict__ Wvb)
{
    const int i = blockIdx.x * 256 + threadIdx.x;
    if (i < 8192)       Wqkb[i] = __float2bfloat16(Wq[i]);
    else if (i < 16384) Wqkb[i] = __float2bfloat16(Wk[i - 8192]);
    else                Wvb[i - 16384] = __float2bfloat16(Wv[i - 16384]);
}

// ---------------------------------------------------------------------------
// Kernel A: q/k/v projection GEMM via bf16 MFMA.
// Outputs: Q,K split bf16 (hi+lo, pixel-major [px][32]);
//          V bf16 pixel-major [px][256] (Vpm) + channel-major [c][px] (Vhw).
// ---------------------------------------------------------------------------
__global__ __launch_bounds__(256) void qkv_mfma(
    const float* __restrict__ in_qk, const float* __restrict__ in_v,
    const __hip_bfloat16* __restrict__ Wqkb, const __hip_bfloat16* __restrict__ Wvb,
    const float* __restrict__ bq, const float* __restrict__ bk,
    const float* __restrict__ bv,
    __hip_bfloat16* __restrict__ Qbh, __hip_bfloat16* __restrict__ Qbl,
    __hip_bfloat16* __restrict__ Kbh, __hip_bfloat16* __restrict__ Kbl,
    __hip_bfloat16* __restrict__ Vpm, __hip_bfloat16* __restrict__ Vhw)
{
    const int b = blockIdx.y;
    const int t = threadIdx.x;
    const int wv = t >> 6, l = t & 63;
    const int n = l & 15, q = l >> 4;            // n = pixel col, q = quad
    const int p = blockIdx.x * 64 + wv * 16 + n; // this lane's pixel
    const size_t bP = (size_t)b * kP;

    const float* __restrict__ xq = in_qk + (size_t)b * kC * kP + p;
    const float* __restrict__ xv = in_v  + (size_t)b * kC * kP + p;

    f32x4 acc[20];
#pragma unroll
    for (int i = 0; i < 20; i++) acc[i] = (f32x4)0.f;

    for (int kc = 0; kc < 8; kc++) {
        const int c0 = kc * 32 + q * 8;
        float fq[8], fv[8];
#pragma unroll
        for (int j = 0; j < 8; j++) fq[j] = xq[(size_t)(c0 + j) * kP];
#pragma unroll
        for (int j = 0; j < 8; j++) fv[j] = xv[(size_t)(c0 + j) * kP];
        union { bf16x8 v; __hip_bfloat16 h[8]; } bfq, bfv;
#pragma unroll
        for (int j = 0; j < 8; j++) bfq.h[j] = __float2bfloat16(fq[j]);
#pragma unroll
        for (int j = 0; j < 8; j++) bfv.h[j] = __float2bfloat16(fv[j]);

#pragma unroll
        for (int mt = 0; mt < 4; mt++) {
            bf16x8 a = *(const bf16x8*)(Wqkb + ((mt * 16 + n) << 8) + c0);
            acc[mt] = __builtin_amdgcn_mfma_f32_16x16x32_bf16(a, bfq.v, acc[mt], 0, 0, 0);
        }
#pragma unroll
        for (int mt = 0; mt < 16; mt++) {
            bf16x8 a = *(const bf16x8*)(Wvb + ((mt * 16 + n) << 8) + c0);
            acc[4 + mt] = __builtin_amdgcn_mfma_f32_16x16x32_bf16(a, bfv.v, acc[4 + mt], 0, 0, 0);
        }
    }

    // ---- epilogue ----
#pragma unroll
    for (int mt = 0; mt < 2; mt++) {      // Q hi/lo
        float4 bias = *(const float4*)&bq[mt * 16 + q * 4];
        float v0 = acc[mt][0] + bias.x, v1 = acc[mt][1] + bias.y;
        float v2 = acc[mt][2] + bias.z, v3 = acc[mt][3] + bias.w;
        union { ushort4 u; __hip_bfloat16 h[4]; } hi, lo;
        float vv[4] = { v0, v1, v2, v3 };
#pragma unroll
        for (int r = 0; r < 4; r++) {
            __hip_bfloat16 h = __float2bfloat16(vv[r]);
            hi.h[r] = h;
            lo.h[r] = __float2bfloat16(vv[r] - __bfloat162float(h));
        }
        *(ushort4*)&Qbh[(bP + p) * kCq + mt * 16 + q * 4] = hi.u;
        *(ushort4*)&Qbl[(bP + p) * kCq + mt * 16 + q * 4] = lo.u;
    }
#pragma unroll
    for (int mt = 2; mt < 4; mt++) {      // K hi/lo
        float4 bias = *(const float4*)&bk[(mt - 2) * 16 + q * 4];
        float vv[4] = { acc[mt][0] + bias.x, acc[mt][1] + bias.y,
                        acc[mt][2] + bias.z, acc[mt][3] + bias.w };
        union { ushort4 u; __hip_bfloat16 h[4]; } hi, lo;
#pragma unroll
        for (int r = 0; r < 4; r++) {
            __hip_bfloat16 h = __float2bfloat16(vv[r]);
            hi.h[r] = h;
            lo.h[r] = __float2bfloat16(vv[r] - __bfloat162float(h));
        }
        *(ushort4*)&Kbh[(bP + p) * kCq + (mt - 2) * 16 + q * 4] = hi.u;
        *(ushort4*)&Kbl[(bP + p) * kCq + (mt - 2) * 16 + q * 4] = lo.u;
    }
#pragma unroll
    for (int mt = 0; mt < 16; mt++) {     // V: pixel-major + channel-major
        float4 bias = *(const float4*)&bv[mt * 16 + q * 4];
        float vv[4] = { acc[4 + mt][0] + bias.x, acc[4 + mt][1] + bias.y,
                        acc[4 + mt][2] + bias.z, acc[4 + mt][3] + bias.w };
        union { ushort4 u; __hip_bfloat16 h[4]; } pm;
#pragma unroll
        for (int r = 0; r < 4; r++) pm.h[r] = __float2bfloat16(vv[r]);
        *(ushort4*)&Vpm[(bP + p) * kC + mt * 16 + q * 4] = pm.u;
#pragma unroll
        for (int r = 0; r < 4; r++)
            Vhw[((size_t)b * kC + mt * 16 + q * 4 + r) * kP + p] = pm.h[r];
    }
}

// ---------------------------------------------------------------------------
// Kernel S: eH stats per column. grid (W, B), block 256.
// E_H = Q_col·K_col^T (96x96) via split-bf16 MFMA; mask diag; row max/sumexp.
// Writes Sm = mH, Si = sH (raw sum).
// ---------------------------------------------------------------------------
__global__ __launch_bounds__(256) void cc_stats(
    const __hip_bfloat16* __restrict__ Qbh, const __hip_bfloat16* __restrict__ Qbl,
    const __hip_bfloat16* __restrict__ Kbh, const __hip_bfloat16* __restrict__ Kbl,
    float* __restrict__ Sm, float* __restrict__ Si)
{
    __shared__ __align__(16) __hip_bfloat16 QH[96][36], QLo[96][36];
    __shared__ __align__(16) __hip_bfloat16 KH[96][36], KLo[96][36];
    __shared__ __align__(16) float EL[96][97];
    const int w = blockIdx.x, b = blockIdx.y;
    const int t = threadIdx.x;
    const size_t bP = (size_t)b * kP;

    for (int idx = t; idx < 768; idx += 256) {
        int row = idx >> 3, ch = (idx & 7) * 4;
        size_t g = (bP + (size_t)row * kW + w) * kCq + ch;
        *(ushort4*)&QH[row][ch]  = *(const ushort4*)&Qbh[g];
        *(ushort4*)&QLo[row][ch] = *(const ushort4*)&Qbl[g];
        *(ushort4*)&KH[row][ch]  = *(const ushort4*)&Kbh[g];
        *(ushort4*)&KLo[row][ch] = *(const ushort4*)&Kbl[g];
    }
    __syncthreads();

    const int wv = t >> 6, l = t & 63, ln = l & 15, lq = l >> 4;
#pragma unroll
    for (int s = 0; s < 9; s++) {
        int tile = wv * 9 + s, it = tile / 6, jt = tile % 6;
        bf16x8 ah = ld_lds8(&QH[it * 16 + ln][lq * 8]);
        bf16x8 al = ld_lds8(&QLo[it * 16 + ln][lq * 8]);
        bf16x8 bh = ld_lds8(&KH[jt * 16 + ln][lq * 8]);
        bf16x8 bl = ld_lds8(&KLo[jt * 16 + ln][lq * 8]);
        f32x4 d = (f32x4)0.f;
        d = __builtin_amdgcn_mfma_f32_16x16x32_bf16(al, bh, d, 0, 0, 0);
        d = __builtin_amdgcn_mfma_f32_16x16x32_bf16(ah, bl, d, 0, 0, 0);
        d = __builtin_amdgcn_mfma_f32_16x16x32_bf16(ah, bh, d, 0, 0, 0);
#pragma unroll
        for (int r = 0; r < 4; r++)
            EL[it * 16 + lq * 4 + r][jt * 16 + ln] = d[r];
    }
    __syncthreads();

    const int sub = t & 7;
    for (int pi = t >> 3; pi < 96; pi += 32) {
        float ev[12];
        float mx = -3.0e38f;
#pragma unroll
        for (int k = 0; k < 12; k++) {
            int j = sub + 8 * k;
            float e = EL[pi][j];
            if (j == pi) e = -3.0e38f;       // diag mask
            ev[k] = e;
            mx = fmaxf(mx, e);
        }
#pragma unroll
        for (int k = 1; k < 8; k <<= 1) mx = fmaxf(mx, __shfl_xor(mx, k, 8));
        float ss = 0.f;
#pragma unroll
        for (int k = 0; k < 12; k++) ss += __expf(ev[k] - mx);
#pragma unroll
        for (int k = 1; k < 8; k <<= 1) ss += __shfl_xor(ss, k, 8);
        if (sub == 0) {
            Sm[bP + (size_t)pi * kW + w] = mx;
            Si[bP + (size_t)pi * kW + w] = ss;
        }
    }
}

// ---------------------------------------------------------------------------
// Kernel B: pass1 (row tiles). grid (3, H, B), block 256 = 4 waves.
// E_W via MFMA -> combine stats -> (m,inv) -> att bf16 -> outW = att x V MFMA
// (V from channel-major global) -> gamma*outW + residual -> Zb. LDS 70.5 KB.
// ---------------------------------------------------------------------------
__global__ __launch_bounds__(256) void cc_pass1(
    const __hip_bfloat16* __restrict__ Qbh, const __hip_bfloat16* __restrict__ Qbl,
    const __hip_bfloat16* __restrict__ Kbh, const __hip_bfloat16* __restrict__ Kbl,
    const __hip_bfloat16* __restrict__ Vhw,
    const float* __restrict__ res_in, const float* __restrict__ gamma_p,
    __hip_bfloat16* __restrict__ Zb, float* __restrict__ Sm, float* __restrict__ Si,
    int s_off)
{
    __shared__ __align__(16) __hip_bfloat16 QH[32][36], QLo[32][36];
    __shared__ __align__(16) __hip_bfloat16 KH[96][36], KLo[96][36];
    __shared__ __align__(16) float EL[32][97];
    __shared__ __align__(16) __hip_bfloat16 attL[32][100];
    __shared__ __align__(16) float rs[32][260];
    const int wt = blockIdx.x, h = blockIdx.y, b = blockIdx.z;
    const int w0 = wt * 32;
    const int t = threadIdx.x;
    const size_t bP = (size_t)b * kP;

    {   // stage Q tile (32 rows)
        int row = t >> 3, ch = (t & 7) * 4;
        size_t g = (bP + (size_t)h * kW + w0 + row) * kCq + ch;
        *(ushort4*)&QH[row][ch]  = *(const ushort4*)&Qbh[g];
        *(ushort4*)&QLo[row][ch] = *(const ushort4*)&Qbl[g];
    }
    for (int idx = t; idx < 768; idx += 256) {   // stage K row (96)
        int row = idx >> 3, ch = (idx & 7) * 4;
        size_t g = (bP + (size_t)h * kW + row) * kCq + ch;
        *(ushort4*)&KH[row][ch]  = *(const ushort4*)&Kbh[g];
        *(ushort4*)&KLo[row][ch] = *(const ushort4*)&Kbl[g];
    }
    const float* __restrict__ res = res_in + (size_t)b * kC * kP + (size_t)h * kW + w0;
    {   // stage residual pixel-major
        const int f4 = t & 7;
        int c2 = t >> 3;
#pragma unroll
        for (int it2 = 0; it2 < 8; it2++, c2 += 32) {
            float4 v = *(const float4*)&res[(size_t)c2 * kP + f4 * 4];
            rs[f4 * 4 + 0][c2] = v.x;
            rs[f4 * 4 + 1][c2] = v.y;
            rs[f4 * 4 + 2][c2] = v.z;
            rs[f4 * 4 + 3][c2] = v.w;
        }
    }
    __syncthreads();

    const int wv = t >> 6, l = t & 63, ln = l & 15, lq = l >> 4;
    // ---- E_W GEMM: 12 tiles, 3 per wave ----
#pragma unroll
    for (int s = 0; s < 3; s++) {
        int tile = wv * 3 + s, it = tile / 6, jt = tile % 6;
        bf16x8 ah = ld_lds8(&QH[it * 16 + ln][lq * 8]);
        bf16x8 al = ld_lds8(&QLo[it * 16 + ln][lq * 8]);
        bf16x8 bh = ld_lds8(&KH[jt * 16 + ln][lq * 8]);
        bf16x8 bl = ld_lds8(&KLo[jt * 16 + ln][lq * 8]);
        f32x4 d = (f32x4)0.f;
        d = __builtin_amdgcn_mfma_f32_16x16x32_bf16(al, bh, d, 0, 0, 0);
        d = __builtin_amdgcn_mfma_f32_16x16x32_bf16(ah, bl, d, 0, 0, 0);
        d = __builtin_amdgcn_mfma_f32_16x16x32_bf16(ah, bh, d, 0, 0, 0);
#pragma unroll
        for (int r = 0; r < 4; r++)
            EL[it * 16 + lq * 4 + r][jt * 16 + ln] = d[r];
    }
    __syncthreads();

    {   // ---- softmax: combine with eH stats; write att bf16 ----
        const int pi = t >> 3, sub = t & 7;
        size_t sidx = bP + (size_t)h * kW + w0 + pi;
        float mH = Sm[sidx], sH = Si[sidx];
        float ev[12];
        float mx = mH;
#pragma unroll
        for (int k = 0; k < 12; k++) {
            float e = EL[pi][sub + 8 * k];
            ev[k] = e;
            mx = fmaxf(mx, e);
        }
#pragma unroll
        for (int k = 1; k < 8; k <<= 1) mx = fmaxf(mx, __shfl_xor(mx, k, 8));
        float ss = 0.f;
#pragma unroll
        for (int k = 0; k < 12; k++) { float e = __expf(ev[k] - mx); ev[k] = e; ss += e; }
#pragma unroll
        for (int k = 1; k < 8; k <<= 1) ss += __shfl_xor(ss, k, 8);
        float stot = ss + sH * __expf(mH - mx);
        float inv = 1.0f / stot;
        if (sub == 0) { Sm[sidx] = mx; Si[sidx] = inv; }
#pragma unroll
        for (int k = 0; k < 12; k++)
            attL[pi][sub + 8 * k] = __float2bfloat16(ev[k] * inv);
    }
    __syncthreads();

    // ---- outW = att (32x96) x V (96x256) via MFMA ----
    bf16x8 aF[2][3];
#pragma unroll
    for (int it = 0; it < 2; it++)
#pragma unroll
        for (int j3 = 0; j3 < 3; j3++)
            aF[it][j3] = ld_lds8(&attL[it * 16 + ln][j3 * 32 + lq * 8]);

    f32x4 acc[2][4];
#pragma unroll
    for (int it = 0; it < 2; it++)
#pragma unroll
        for (int c4 = 0; c4 < 4; c4++) acc[it][c4] = (f32x4)0.f;

#pragma unroll
    for (int c4 = 0; c4 < 4; c4++) {
        const int c = (wv * 4 + c4) * 16 + ln;
        const __hip_bfloat16* vr = Vhw + ((size_t)b * kC + c) * kP + (size_t)h * kW;
        bf16x8 bF0 = *(const bf16x8*)&vr[lq * 8];
        bf16x8 bF1 = *(const bf16x8*)&vr[32 + lq * 8];
        bf16x8 bF2 = *(const bf16x8*)&vr[64 + lq * 8];
#pragma unroll
        for (int it = 0; it < 2; it++) {
            acc[it][c4] = __builtin_amdgcn_mfma_f32_16x16x32_bf16(aF[it][0], bF0, acc[it][c4], 0, 0, 0);
            acc[it][c4] = __builtin_amdgcn_mfma_f32_16x16x32_bf16(aF[it][1], bF1, acc[it][c4], 0, 0, 0);
            acc[it][c4] = __builtin_amdgcn_mfma_f32_16x16x32_bf16(aF[it][2], bF2, acc[it][c4], 0, 0, 0);
        }
    }

    // ---- epilogue: gamma*outW + residual -> Zb bf16 ----
    const float gamma = gamma_p[0];
#pragma unroll
    for (int c4 = 0; c4 < 4; c4++) {
        const int c = (wv * 4 + c4) * 16 + ln;
#pragma unroll
        for (int it = 0; it < 2; it++) {
#pragma unroll
            for (int r = 0; r < 4; r++) {
                int i = it * 16 + lq * 4 + r;
                float z = gamma * acc[it][c4][r] + rs[i][c];
                Zb[(bP + (size_t)h * kW + w0 + i) * 512 + s_off + c] = __float2bfloat16(z);
            }
        }
    }
}

// ---------------------------------------------------------------------------
// Kernel C: pass2 (column tiles). grid (3, W, B), block 256.
// Recompute E_H via MFMA, att from stored (m,inv), outH = att x V_col MFMA
// (V staged from pixel-major global), Zb RMW. LDS 74.8 KB.
// ---------------------------------------------------------------------------
__global__ __launch_bounds__(256) void cc_pass2(
    const __hip_bfloat16* __restrict__ Qbh, const __hip_bfloat16* __restrict__ Qbl,
    const __hip_bfloat16* __restrict__ Kbh, const __hip_bfloat16* __restrict__ Kbl,
    const __hip_bfloat16* __restrict__ Vpm,
    const float* __restrict__ gamma_p, __hip_bfloat16* __restrict__ Zb,
    const float* __restrict__ Sm, const float* __restrict__ Si, int s_off)
{
    __shared__ __align__(16) __hip_bfloat16 QH[32][36], QLo[32][36];
    __shared__ __align__(16) __hip_bfloat16 KH[96][36], KLo[96][36];
    __shared__ __align__(16) __hip_bfloat16 VL[96][260];
    __shared__ __align__(16) __hip_bfloat16 attL[32][100];
    const int ht = blockIdx.x, w = blockIdx.y, b = blockIdx.z;
    const int h0 = ht * 32;
    const int t = threadIdx.x;
    const size_t bP = (size_t)b * kP;

    {   // stage Q (rows h0..h0+31 at column w)
        int row = t >> 3, ch = (t & 7) * 4;
        size_t g = (bP + (size_t)(h0 + row) * kW + w) * kCq + ch;
        *(ushort4*)&QH[row][ch]  = *(const ushort4*)&Qbh[g];
        *(ushort4*)&QLo[row][ch] = *(const ushort4*)&Qbl[g];
    }
    for (int idx = t; idx < 768; idx += 256) {   // stage K column (96 rows)
        int row = idx >> 3, ch = (idx & 7) * 4;
        size_t g = (bP + (size_t)row * kW + w) * kCq + ch;
        *(ushort4*)&KH[row][ch]  = *(const ushort4*)&Kbh[g];
        *(ushort4*)&KLo[row][ch] = *(const ushort4*)&Kbl[g];
    }
    for (int idx = t; idx < 96 * 32; idx += 256) {  // stage V column
        int j = idx >> 5, cg = (idx & 31) * 8;
        const ushort4* src = (const ushort4*)&Vpm[(bP + (size_t)j * kW + w) * kC + cg];
        ushort4 v0 = src[0], v1 = src[1];
        *(ushort4*)&VL[j][cg]     = v0;
        *(ushort4*)&VL[j][cg + 4] = v1;
    }
    __syncthreads();

    const int wv = t >> 6, l = t & 63, ln = l & 15, lq = l >> 4;
    // ---- E_H GEMM -> att directly (no fp32 E buffer) ----
#pragma unroll
    for (int s = 0; s < 3; s++) {
        int tile = wv * 3 + s, it = tile / 6, jt = tile % 6;
        bf16x8 ah = ld_lds8(&QH[it * 16 + ln][lq * 8]);
        bf16x8 al = ld_lds8(&QLo[it * 16 + ln][lq * 8]);
        bf16x8 bh = ld_lds8(&KH[jt * 16 + ln][lq * 8]);
        bf16x8 bl = ld_lds8(&KLo[jt * 16 + ln][lq * 8]);
        f32x4 d = (f32x4)0.f;
        d = __builtin_amdgcn_mfma_f32_16x16x32_bf16(al, bh, d, 0, 0, 0);
        d = __builtin_amdgcn_mfma_f32_16x16x32_bf16(ah, bl, d, 0, 0, 0);
        d = __builtin_amdgcn_mfma_f32_16x16x32_bf16(ah, bh, d, 0, 0, 0);
        const int j = jt * 16 + ln;
#pragma unroll
        for (int r = 0; r < 4; r++) {
            int i = it * 16 + lq * 4 + r;
            size_t sidx = bP + (size_t)(h0 + i) * kW + w;
            float m = Sm[sidx], inv = Si[sidx];
            float a = (j == h0 + i) ? 0.f : __expf(d[r] - m) * inv;
            attL[i][j] = __float2bfloat16(a);
        }
    }
    __syncthreads();

    // ---- outH = att (32x96) x V_col (96x256) ----
    bf16x8 aF[2][3];
#pragma unroll
    for (int it = 0; it < 2; it++)
#pragma unroll
        for (int j3 = 0; j3 < 3; j3++)
            aF[it][j3] = ld_lds8(&attL[it * 16 + ln][j3 * 32 + lq * 8]);

    f32x4 acc[2][4];
#pragma unroll
    for (int it = 0; it < 2; it++)
#pragma unroll
        for (int c4 = 0; c4 < 4; c4++) acc[it][c4] = (f32x4)0.f;

#pragma unroll
    for (int c4 = 0; c4 < 4; c4++) {
        const int c = (wv * 4 + c4) * 16 + ln;
#pragma unroll
        for (int j3 = 0; j3 < 3; j3++) {
            union { bf16x8 v; __hip_bfloat16 h[8]; } bF;
#pragma unroll
            for (int jj = 0; jj < 8; jj++)
                bF.h[jj] = VL[j3 * 32 + lq * 8 + jj][c];
#pragma unroll
            for (int it = 0; it < 2; it++)
                acc[it][c4] = __builtin_amdgcn_mfma_f32_16x16x32_bf16(aF[it][j3], bF.v, acc[it][c4], 0, 0, 0);
        }
    }

    // ---- epilogue: Zb RMW ----
    const float gamma = gamma_p[0];
#pragma unroll
    for (int c4 = 0; c4 < 4; c4++) {
        const int c = (wv * 4 + c4) * 16 + ln;
#pragma unroll
        for (int it = 0; it < 2; it++) {
#pragma unroll
            for (int r = 0; r < 4; r++) {
                int i = it * 16 + lq * 4 + r;
                size_t zi = (bP + (size_t)(h0 + i) * kW + w) * 512 + s_off + c;
                float old = __bfloat162float(Zb[zi]);
                Zb[zi] = __float2bfloat16(old + gamma * acc[it][c4][r]);
            }
        }
    }
}

// ---------------------------------------------------------------------------
// Kernel W2: convert Wp [256][512] fp32 -> bf16 (into dead Qb region).
// ---------------------------------------------------------------------------
__global__ __launch_bounds__(256) void wp_convert(
    const float* __restrict__ Wp, __hip_bfloat16* __restrict__ Wpb)
{
    const int i = blockIdx.x * 256 + threadIdx.x;
    Wpb[i] = __float2bfloat16(Wp[i]);
}

// ---------------------------------------------------------------------------
// Kernel D: fused depthwise 3x3 + pointwise 512->256 (bf16 MFMA) + leaky relu.
// (unchanged)
// ---------------------------------------------------------------------------
__global__ __launch_bounds__(256) void dwpw(
    const __hip_bfloat16* __restrict__ Zb,
    const float* __restrict__ Wdw, const float* __restrict__ bd,
    const __hip_bfloat16* __restrict__ Wpb, const float* __restrict__ bp,
    float* __restrict__ out)
{
    __shared__ __align__(16) char smem[33792];
    __hip_bfloat16 (*zs)[520] = (__hip_bfloat16 (*)[520])smem;

    const int wt = blockIdx.x, h = blockIdx.y, b = blockIdx.z;
    const int w0 = wt * 32;
    const int t = threadIdx.x;
    const size_t bP = (size_t)b * kP;

    {
        float wd0[9], wd1[9];
#pragma unroll
        for (int k = 0; k < 9; k++) {
            wd0[k] = Wdw[(size_t)(2 * t) * 9 + k];
            wd1[k] = Wdw[(size_t)(2 * t + 1) * 9 + k];
        }
        const float b0 = bd[2 * t], b1 = bd[2 * t + 1];
        const __hip_bfloat162* __restrict__ Zp =
            (const __hip_bfloat162*)Zb + bP * 256 + t;
        const bool rvm = (h > 0), rvp = (h < kH - 1);

#pragma unroll
        for (int j0 = 0; j0 < 32; j0 += 8) {
            float2 wf[10][3];
#pragma unroll
            for (int col = 0; col < 10; col++) {
                const int ww = w0 + j0 - 1 + col;
                const bool cv = (ww >= 0) && (ww < kW);
#pragma unroll
                for (int r = 0; r < 3; r++) {
                    const bool v = cv && (r == 1 || (r == 0 ? rvm : rvp));
                    __hip_bfloat162 z2;
                    z2.x = __ushort_as_bfloat16(0);
                    z2.y = __ushort_as_bfloat16(0);
                    if (v) z2 = Zp[(size_t)((h + r - 1) * kW + ww) * 256];
                    wf[col][r] = __bfloat1622float2(z2);
                }
            }
#pragma unroll
            for (int j = 0; j < 8; j++) {
                float a0 = b0, a1 = b1;
#pragma unroll
                for (int r = 0; r < 3; r++) {
#pragma unroll
                    for (int dw = 0; dw < 3; dw++) {
                        const float2 z = wf[j + dw][r];
                        const int k = r * 3 + dw;
                        a0 += wd0[k] * z.x;
                        a1 += wd1[k] * z.y;
                    }
                }
                __hip_bfloat162 pz;
                pz.x = __float2bfloat16(a0);
                pz.y = __float2bfloat16(a1);
                ((__hip_bfloat162*)&zs[j0 + j][0])[t] = pz;
            }
        }
    }
    __syncthreads();

    const int l = t & 63, wv = t >> 6;
    const int lo16 = l & 15, q = l >> 4;

    f32x4 acc[2][4];
#pragma unroll
    for (int mt = 0; mt < 2; mt++)
#pragma unroll
        for (int nt = 0; nt < 4; nt++) acc[mt][nt] = (f32x4)0.f;

    const bf16x8* __restrict__ Bb[4];
#pragma unroll
    for (int nt = 0; nt < 4; nt++)
        Bb[nt] = (const bf16x8*)(Wpb + (size_t)(wv * 64 + nt * 16 + lo16) * 512);

    for (int kc = 0; kc < 16; kc++) {
        bf16x8 a0 = *(const bf16x8*)&zs[lo16][kc * 32 + q * 8];
        bf16x8 a1 = *(const bf16x8*)&zs[16 + lo16][kc * 32 + q * 8];
#pragma unroll
        for (int nt = 0; nt < 4; nt++) {
            bf16x8 bf = Bb[nt][kc * 4 + q];
            acc[0][nt] = __builtin_amdgcn_mfma_f32_16x16x32_bf16(a0, bf, acc[0][nt], 0, 0, 0);
            acc[1][nt] = __builtin_amdgcn_mfma_f32_16x16x32_bf16(a1, bf, acc[1][nt], 0, 0, 0);
        }
    }
    __syncthreads();

    float* os = (float*)smem + (size_t)wv * 64 * 33;
#pragma unroll
    for (int nt = 0; nt < 4; nt++) {
        const int ol = nt * 16 + lo16;
        const float bias = bp[wv * 64 + ol];
#pragma unroll
        for (int mt = 0; mt < 2; mt++) {
#pragma unroll
            for (int r = 0; r < 4; r++) {
                float v = acc[mt][nt][r] + bias;
                v = v > 0.f ? v : 0.01f * v;
                os[ol * 33 + mt * 16 + q * 4 + r] = v;
            }
        }
    }
    __syncthreads();
    const int px = l & 31, oh = l >> 5;
    for (int j = 0; j < 32; j++) {
        const int ol = j * 2 + oh;
        out[((size_t)b * 256 + wv * 64 + ol) * kP + (size_t)h * kW + w0 + px] =
            os[ol * 33 + px];
    }
}

// ---------------------------------------------------------------------------
extern "C" void kernel_launch(void* const* d_in, const int* in_sizes, int n_in,
                              void* d_out, int out_size, void* d_ws, size_t ws_size,
                              hipStream_t stream)
{
    const float* x   = (const float*)d_in[0];
    const float* y   = (const float*)d_in[1];
    const float* Wq  = (const float*)d_in[2];
    const float* bq  = (const float*)d_in[3];
    const float* Wk  = (const float*)d_in[4];
    const float* bk  = (const float*)d_in[5];
    const float* Wv  = (const float*)d_in[6];
    const float* bv  = (const float*)d_in[7];
    const float* g1  = (const float*)d_in[8];
    const float* g2  = (const float*)d_in[9];
    const float* Wdw = (const float*)d_in[10];
    const float* bd  = (const float*)d_in[11];
    const float* Wp  = (const float*)d_in[12];
    const float* bp  = (const float*)d_in[13];
    float* out = (float*)d_out;

    // Workspace layout (94,961,664 B total — identical size to prior rounds):
    //   Zb       : bf16 [8][9216][512]      = 75,497,472
    //   Qb hi/lo : bf16 2x[8][9216][32]     =  9,437,184
    //   Kb hi/lo : bf16 2x[8][9216][32]     =  9,437,184
    //   Sm, Si   : fp32 [8][9216]           =    294,912 each
    // V (bf16, two layouts) lives in d_out until dwpw:
    //   Vpm [8][9216][256] @ +0, Vhw [8][256][9216] @ +37,748,736 (= 75.5 MB).
    // Wqkb/Wvb alias the (dead at qkv time) Sm region; Wpb aliases Qb region.
    char* wsb = (char*)d_ws;
    __hip_bfloat16* Zb  = (__hip_bfloat16*)wsb;
    __hip_bfloat16* Qbh = (__hip_bfloat16*)(wsb + 75497472);
    __hip_bfloat16* Qbl = Qbh + 2359296;
    __hip_bfloat16* Kbh = (__hip_bfloat16*)(wsb + 84934656);
    __hip_bfloat16* Kbl = Kbh + 2359296;
    float* Sm = (float*)(wsb + 94371840);
    float* Si = (float*)(wsb + 94666752);
    __hip_bfloat16* Wqkb = (__hip_bfloat16*)Sm;
    __hip_bfloat16* Wvb  = ((__hip_bfloat16*)Sm) + 16384;
    __hip_bfloat16* Wpb  = (__hip_bfloat16*)(wsb + 75497472);  // dead Qb region
    __hip_bfloat16* Vpm  = (__hip_bfloat16*)d_out;
    __hip_bfloat16* Vhw  = Vpm + 18874368;

    // stream 1: q,k from x; v from y; residual x; channels [0,256)
    hipLaunchKernelGGL(w_convert, dim3(320), dim3(256), 0, stream,
                       Wq, Wk, Wv, Wqkb, Wvb);
    hipLaunchKernelGGL(qkv_mfma, dim3(kP / 64, kB), dim3(256), 0, stream,
                       x, y, Wqkb, Wvb, bq, bk, bv, Qbh, Qbl, Kbh, Kbl, Vpm, Vhw);
    hipLaunchKernelGGL(cc_stats, dim3(kW, kB), dim3(256), 0, stream,
                       Qbh, Qbl, Kbh, Kbl, Sm, Si);
    hipLaunchKernelGGL(cc_pass1, dim3(kW / 32, kH, kB), dim3(256), 0, stream,
                       Qbh, Qbl, Kbh, Kbl, Vhw, x, g1, Zb, Sm, Si, 0);
    hipLaunchKernelGGL(cc_pass2, dim3(kH / 32, kW, kB), dim3(256), 0, stream,
                       Qbh, Qbl, Kbh, Kbl, Vpm, g1, Zb, Sm, Si, 0);
    // stream 2: q,k from y; v from x; residual y; channels [256,512)
    hipLaunchKernelGGL(w_convert, dim3(320), dim3(256), 0, stream,
                       Wq, Wk, Wv, Wqkb, Wvb);
    hipLaunchKernelGGL(qkv_mfma, dim3(kP / 64, kB), dim3(256), 0, stream,
                       y, x, Wqkb, Wvb, bq, bk, bv, Qbh, Qbl, Kbh, Kbl, Vpm, Vhw);
    hipLaunchKernelGGL(cc_stats, dim3(kW, kB), dim3(256), 0, stream,
                       Qbh, Qbl, Kbh, Kbl, Sm, Si);
    hipLaunchKernelGGL(cc_pass1, dim3(kW / 32, kH, kB), dim3(256), 0, stream,
                       Qbh, Qbl, Kbh, Kbl, Vhw, y, g2, Zb, Sm, Si, 256);
    hipLaunchKernelGGL(cc_pass2, dim3(kH / 32, kW, kB), dim3(256), 0, stream,
                       Qbh, Qbl, Kbh, Kbl, Vpm, g2, Zb, Sm, Si, 256);
    // convert Wp to bf16 (Qb region dead now)
    hipLaunchKernelGGL(wp_convert, dim3(512), dim3(256), 0, stream, Wp, Wpb);
    // fused depthwise + pointwise MFMA + leaky relu (overwrites d_out)
    hipLaunchKernelGGL(dwpw, dim3(kW / 32, kH, kB), dim3(256), 0, stream,
                       Zb, Wdw, bd, Wpb, bp, out);
}

// Round 3
// 919.392 us; speedup vs baseline: 1.4624x; 1.0630x over previous
//
#include <hip/hip_runtime.h>
#include <hip/hip_bf16.h>

constexpr int kB  = 8;
constexpr int kC  = 256;
constexpr int kCq = 32;
constexpr int kH  = 96;
constexpr int kW  = 96;
constexpr int kP  = kH * kW;      // 9216

using bf16x8 = __attribute__((ext_vector_type(8))) short;
using bf16x4 = __attribute__((ext_vector_type(4))) short;
using f32x4  = __attribute__((ext_vector_type(4))) float;

// load 8 bf16 from 8B-aligned LDS as two b64 reads
__device__ inline bf16x8 ld_lds8(const __hip_bfloat16* p) {
    bf16x4 lo = *(const bf16x4*)p;
    bf16x4 hi = *(const bf16x4*)(p + 4);
    return __builtin_shufflevector(lo, hi, 0, 1, 2, 3, 4, 5, 6, 7);
}

// ---------------------------------------------------------------------------
// Kernel W1: convert Wq+Wk -> Wqkb [64][256] bf16, Wv -> Wvb [256][256] bf16.
// ---------------------------------------------------------------------------
__global__ __launch_bounds__(256) void w_convert(
    const float* __restrict__ Wq, const float* __restrict__ Wk,
    const float* __restrict__ Wv,
    __hip_bfloat16* __restrict__ Wqkb, __hip_bfloat16* __restrict__ Wvb)
{
    const int i = blockIdx.x * 256 + threadIdx.x;
    if (i < 8192)       Wqkb[i] = __float2bfloat16(Wq[i]);
    else if (i < 16384) Wqkb[i] = __float2bfloat16(Wk[i - 8192]);
    else                Wvb[i - 16384] = __float2bfloat16(Wv[i - 16384]);
}

// ---------------------------------------------------------------------------
// Kernel A v3: q/k/v projection GEMM via bf16 MFMA.
// LDS-staged coalesced float4 input loads (double-buffered, prefetch ahead of
// MFMA) + LDS-transposed Vhw epilogue (16B stores instead of 2B scatter).
// grid (144, B), block 256 = 4 waves; per wave 16 pixels x 320 outputs.
// ---------------------------------------------------------------------------
__global__ __launch_bounds__(256) void qkv_mfma(
    const float* __restrict__ in_qk, const float* __restrict__ in_v,
    const __hip_bfloat16* __restrict__ Wqkb, const __hip_bfloat16* __restrict__ Wvb,
    const float* __restrict__ bq, const float* __restrict__ bk,
    const float* __restrict__ bv,
    __hip_bfloat16* __restrict__ Qbh, __hip_bfloat16* __restrict__ Qbl,
    __hip_bfloat16* __restrict__ Kbh, __hip_bfloat16* __restrict__ Kbl,
    __hip_bfloat16* __restrict__ Vpm, __hip_bfloat16* __restrict__ Vhw)
{
    // smem: staging sq[2][64][36] (9216B) + sv[2][64][36] (9216B) = 18432B,
    // aliased by vt[256][68] (34816B) in the epilogue.
    __shared__ __align__(16) char smem[34816];
    __hip_bfloat16* sqb = (__hip_bfloat16*)smem;        // [2][64][36]
    __hip_bfloat16* svb = sqb + 2 * 64 * 36;            // [2][64][36]
    __hip_bfloat16* vt  = (__hip_bfloat16*)smem;        // [256][68] alias

    const int b = blockIdx.y, t = threadIdx.x;
    const int wv = t >> 6, l = t & 63;
    const int n = l & 15, q = l >> 4;            // n = pixel col, q = quad
    const int p0 = blockIdx.x * 64;
    const int p  = p0 + wv * 16 + n;             // this lane's pixel
    const size_t bP = (size_t)b * kP;

    const float* __restrict__ xq = in_qk + (size_t)b * kC * kP + p0;
    const float* __restrict__ xv = in_v  + (size_t)b * kC * kP + p0;

    // staging mapping: thread -> (channel sc, pixel group sp of 4)
    const int sc = t >> 4;            // 0..15
    const int sp = (t & 15) * 4;      // 0,4,...,60

    f32x4 acc[20];
#pragma unroll
    for (int i = 0; i < 20; i++) acc[i] = (f32x4)0.f;

    // ---- prologue: load + stage chunk 0 ----
    {
        float4 q0 = *(const float4*)&xq[(size_t)sc * kP + sp];
        float4 q1 = *(const float4*)&xq[(size_t)(16 + sc) * kP + sp];
        float4 v0 = *(const float4*)&xv[(size_t)sc * kP + sp];
        float4 v1 = *(const float4*)&xv[(size_t)(16 + sc) * kP + sp];
        float fq0[4] = { q0.x, q0.y, q0.z, q0.w };
        float fq1[4] = { q1.x, q1.y, q1.z, q1.w };
        float fv0[4] = { v0.x, v0.y, v0.z, v0.w };
        float fv1[4] = { v1.x, v1.y, v1.z, v1.w };
#pragma unroll
        for (int j = 0; j < 4; j++) {
            sqb[(sp + j) * 36 + sc]      = __float2bfloat16(fq0[j]);
            sqb[(sp + j) * 36 + 16 + sc] = __float2bfloat16(fq1[j]);
            svb[(sp + j) * 36 + sc]      = __float2bfloat16(fv0[j]);
            svb[(sp + j) * 36 + 16 + sc] = __float2bfloat16(fv1[j]);
        }
    }
    __syncthreads();

    int cur = 0;
    for (int kc = 0; kc < 8; kc++) {
        // ---- issue next chunk's global loads (latency hides under MFMA) ----
        float4 nq0, nq1, nv0, nv1;
        if (kc < 7) {
            const size_t cb = (size_t)(kc + 1) * 32;
            nq0 = *(const float4*)&xq[(cb + sc) * kP + sp];
            nq1 = *(const float4*)&xq[(cb + 16 + sc) * kP + sp];
            nv0 = *(const float4*)&xv[(cb + sc) * kP + sp];
            nv1 = *(const float4*)&xv[(cb + 16 + sc) * kP + sp];
        }

        // ---- B fragments from LDS ----
        const __hip_bfloat16* sqp = sqb + cur * 2304 + (wv * 16 + n) * 36 + q * 8;
        const __hip_bfloat16* svp = svb + cur * 2304 + (wv * 16 + n) * 36 + q * 8;
        bf16x8 bfq = ld_lds8(sqp);
        bf16x8 bfv = ld_lds8(svp);
        const int c0 = kc * 32 + q * 8;

#pragma unroll
        for (int mt = 0; mt < 4; mt++) {
            bf16x8 a = *(const bf16x8*)(Wqkb + ((mt * 16 + n) << 8) + c0);
            acc[mt] = __builtin_amdgcn_mfma_f32_16x16x32_bf16(a, bfq, acc[mt], 0, 0, 0);
        }
#pragma unroll
        for (int mt = 0; mt < 16; mt++) {
            bf16x8 a = *(const bf16x8*)(Wvb + ((mt * 16 + n) << 8) + c0);
            acc[4 + mt] = __builtin_amdgcn_mfma_f32_16x16x32_bf16(a, bfv, acc[4 + mt], 0, 0, 0);
        }

        // ---- stage next chunk into the other buffer ----
        if (kc < 7) {
            const int nb = cur ^ 1;
            __hip_bfloat16* dq = sqb + nb * 2304;
            __hip_bfloat16* dv = svb + nb * 2304;
            float fq0[4] = { nq0.x, nq0.y, nq0.z, nq0.w };
            float fq1[4] = { nq1.x, nq1.y, nq1.z, nq1.w };
            float fv0[4] = { nv0.x, nv0.y, nv0.z, nv0.w };
            float fv1[4] = { nv1.x, nv1.y, nv1.z, nv1.w };
#pragma unroll
            for (int j = 0; j < 4; j++) {
                dq[(sp + j) * 36 + sc]      = __float2bfloat16(fq0[j]);
                dq[(sp + j) * 36 + 16 + sc] = __float2bfloat16(fq1[j]);
                dv[(sp + j) * 36 + sc]      = __float2bfloat16(fv0[j]);
                dv[(sp + j) * 36 + 16 + sc] = __float2bfloat16(fv1[j]);
            }
        }
        __syncthreads();
        cur ^= 1;
    }

    // ---- epilogue: Q/K split hi+lo (pixel-major) ----
#pragma unroll
    for (int mt = 0; mt < 2; mt++) {
        float4 bias = *(const float4*)&bq[mt * 16 + q * 4];
        float vv[4] = { acc[mt][0] + bias.x, acc[mt][1] + bias.y,
                        acc[mt][2] + bias.z, acc[mt][3] + bias.w };
        union { ushort4 u; __hip_bfloat16 h[4]; } hi, lo;
#pragma unroll
        for (int r = 0; r < 4; r++) {
            __hip_bfloat16 h = __float2bfloat16(vv[r]);
            hi.h[r] = h;
            lo.h[r] = __float2bfloat16(vv[r] - __bfloat162float(h));
        }
        *(ushort4*)&Qbh[(bP + p) * kCq + mt * 16 + q * 4] = hi.u;
        *(ushort4*)&Qbl[(bP + p) * kCq + mt * 16 + q * 4] = lo.u;
    }
#pragma unroll
    for (int mt = 2; mt < 4; mt++) {
        float4 bias = *(const float4*)&bk[(mt - 2) * 16 + q * 4];
        float vv[4] = { acc[mt][0] + bias.x, acc[mt][1] + bias.y,
                        acc[mt][2] + bias.z, acc[mt][3] + bias.w };
        union { ushort4 u; __hip_bfloat16 h[4]; } hi, lo;
#pragma unroll
        for (int r = 0; r < 4; r++) {
            __hip_bfloat16 h = __float2bfloat16(vv[r]);
            hi.h[r] = h;
            lo.h[r] = __float2bfloat16(vv[r] - __bfloat162float(h));
        }
        *(ushort4*)&Kbh[(bP + p) * kCq + (mt - 2) * 16 + q * 4] = hi.u;
        *(ushort4*)&Kbl[(bP + p) * kCq + (mt - 2) * 16 + q * 4] = lo.u;
    }

    // ---- V: Vpm (pixel-major) global + vt LDS transpose for Vhw ----
    // (all LDS reads of sq/sv completed at the final loop barrier; vt aliases)
#pragma unroll
    for (int mt = 0; mt < 16; mt++) {
        float4 bias = *(const float4*)&bv[mt * 16 + q * 4];
        float vv[4] = { acc[4 + mt][0] + bias.x, acc[4 + mt][1] + bias.y,
                        acc[4 + mt][2] + bias.z, acc[4 + mt][3] + bias.w };
        union { ushort4 u; __hip_bfloat16 h[4]; } pm;
#pragma unroll
        for (int r = 0; r < 4; r++) pm.h[r] = __float2bfloat16(vv[r]);
        *(ushort4*)&Vpm[(bP + p) * kC + mt * 16 + q * 4] = pm.u;
#pragma unroll
        for (int r = 0; r < 4; r++)
            vt[(mt * 16 + q * 4 + r) * 68 + wv * 16 + n] = pm.h[r];
    }
    __syncthreads();

    // each thread writes its channel's 64-pixel row as 8 x 16B stores
    {
        __hip_bfloat16* dst = Vhw + ((size_t)b * kC + t) * kP + p0;
#pragma unroll
        for (int j = 0; j < 8; j++) {
            bf16x8 row = ld_lds8(&vt[t * 68 + j * 8]);
            *(bf16x8*)&dst[j * 8] = row;
        }
    }
}

// ---------------------------------------------------------------------------
// Kernel S: eH stats per column. grid (W, B), block 256.
// E_H = Q_col·K_col^T (96x96) via split-bf16 MFMA; mask diag; row max/sumexp.
// Writes Sm = mH, Si = sH (raw sum).
// ---------------------------------------------------------------------------
__global__ __launch_bounds__(256) void cc_stats(
    const __hip_bfloat16* __restrict__ Qbh, const __hip_bfloat16* __restrict__ Qbl,
    const __hip_bfloat16* __restrict__ Kbh, const __hip_bfloat16* __restrict__ Kbl,
    float* __restrict__ Sm, float* __restrict__ Si)
{
    __shared__ __align__(16) __hip_bfloat16 QH[96][36], QLo[96][36];
    __shared__ __align__(16) __hip_bfloat16 KH[96][36], KLo[96][36];
    __shared__ __align__(16) float EL[96][97];
    const int w = blockIdx.x, b = blockIdx.y;
    const int t = threadIdx.x;
    const size_t bP = (size_t)b * kP;

    for (int idx = t; idx < 768; idx += 256) {
        int row = idx >> 3, ch = (idx & 7) * 4;
        size_t g = (bP + (size_t)row * kW + w) * kCq + ch;
        *(ushort4*)&QH[row][ch]  = *(const ushort4*)&Qbh[g];
        *(ushort4*)&QLo[row][ch] = *(const ushort4*)&Qbl[g];
        *(ushort4*)&KH[row][ch]  = *(const ushort4*)&Kbh[g];
        *(ushort4*)&KLo[row][ch] = *(const ushort4*)&Kbl[g];
    }
    __syncthreads();

    const int wv = t >> 6, l = t & 63, ln = l & 15, lq = l >> 4;
#pragma unroll
    for (int s = 0; s < 9; s++) {
        int tile = wv * 9 + s, it = tile / 6, jt = tile % 6;
        bf16x8 ah = ld_lds8(&QH[it * 16 + ln][lq * 8]);
        bf16x8 al = ld_lds8(&QLo[it * 16 + ln][lq * 8]);
        bf16x8 bh = ld_lds8(&KH[jt * 16 + ln][lq * 8]);
        bf16x8 bl = ld_lds8(&KLo[jt * 16 + ln][lq * 8]);
        f32x4 d = (f32x4)0.f;
        d = __builtin_amdgcn_mfma_f32_16x16x32_bf16(al, bh, d, 0, 0, 0);
        d = __builtin_amdgcn_mfma_f32_16x16x32_bf16(ah, bl, d, 0, 0, 0);
        d = __builtin_amdgcn_mfma_f32_16x16x32_bf16(ah, bh, d, 0, 0, 0);
#pragma unroll
        for (int r = 0; r < 4; r++)
            EL[it * 16 + lq * 4 + r][jt * 16 + ln] = d[r];
    }
    __syncthreads();

    const int sub = t & 7;
    for (int pi = t >> 3; pi < 96; pi += 32) {
        float ev[12];
        float mx = -3.0e38f;
#pragma unroll
        for (int k = 0; k < 12; k++) {
            int j = sub + 8 * k;
            float e = EL[pi][j];
            if (j == pi) e = -3.0e38f;       // diag mask
            ev[k] = e;
            mx = fmaxf(mx, e);
        }
#pragma unroll
        for (int k = 1; k < 8; k <<= 1) mx = fmaxf(mx, __shfl_xor(mx, k, 8));
        float ss = 0.f;
#pragma unroll
        for (int k = 0; k < 12; k++) ss += __expf(ev[k] - mx);
#pragma unroll
        for (int k = 1; k < 8; k <<= 1) ss += __shfl_xor(ss, k, 8);
        if (sub == 0) {
            Sm[bP + (size_t)pi * kW + w] = mx;
            Si[bP + (size_t)pi * kW + w] = ss;
        }
    }
}

// ---------------------------------------------------------------------------
// Kernel B: pass1 (row tiles). grid (3, H, B), block 256 = 4 waves.
// E_W via MFMA -> combine stats -> (m,inv) -> att bf16 -> outW = att x V MFMA
// (V from channel-major global) -> gamma*outW + residual -> Zb. LDS 70.5 KB.
// ---------------------------------------------------------------------------
__global__ __launch_bounds__(256) void cc_pass1(
    const __hip_bfloat16* __restrict__ Qbh, const __hip_bfloat16* __restrict__ Qbl,
    const __hip_bfloat16* __restrict__ Kbh, const __hip_bfloat16* __restrict__ Kbl,
    const __hip_bfloat16* __restrict__ Vhw,
    const float* __restrict__ res_in, const float* __restrict__ gamma_p,
    __hip_bfloat16* __restrict__ Zb, float* __restrict__ Sm, float* __restrict__ Si,
    int s_off)
{
    __shared__ __align__(16) __hip_bfloat16 QH[32][36], QLo[32][36];
    __shared__ __align__(16) __hip_bfloat16 KH[96][36], KLo[96][36];
    __shared__ __align__(16) float EL[32][97];
    __shared__ __align__(16) __hip_bfloat16 attL[32][100];
    __shared__ __align__(16) float rs[32][260];
    const int wt = blockIdx.x, h = blockIdx.y, b = blockIdx.z;
    const int w0 = wt * 32;
    const int t = threadIdx.x;
    const size_t bP = (size_t)b * kP;

    {   // stage Q tile (32 rows)
        int row = t >> 3, ch = (t & 7) * 4;
        size_t g = (bP + (size_t)h * kW + w0 + row) * kCq + ch;
        *(ushort4*)&QH[row][ch]  = *(const ushort4*)&Qbh[g];
        *(ushort4*)&QLo[row][ch] = *(const ushort4*)&Qbl[g];
    }
    for (int idx = t; idx < 768; idx += 256) {   // stage K row (96)
        int row = idx >> 3, ch = (idx & 7) * 4;
        size_t g = (bP + (size_t)h * kW + row) * kCq + ch;
        *(ushort4*)&KH[row][ch]  = *(const ushort4*)&Kbh[g];
        *(ushort4*)&KLo[row][ch] = *(const ushort4*)&Kbl[g];
    }
    const float* __restrict__ res = res_in + (size_t)b * kC * kP + (size_t)h * kW + w0;
    {   // stage residual pixel-major
        const int f4 = t & 7;
        int c2 = t >> 3;
#pragma unroll
        for (int it2 = 0; it2 < 8; it2++, c2 += 32) {
            float4 v = *(const float4*)&res[(size_t)c2 * kP + f4 * 4];
            rs[f4 * 4 + 0][c2] = v.x;
            rs[f4 * 4 + 1][c2] = v.y;
            rs[f4 * 4 + 2][c2] = v.z;
            rs[f4 * 4 + 3][c2] = v.w;
        }
    }
    __syncthreads();

    const int wv = t >> 6, l = t & 63, ln = l & 15, lq = l >> 4;
    // ---- E_W GEMM: 12 tiles, 3 per wave ----
#pragma unroll
    for (int s = 0; s < 3; s++) {
        int tile = wv * 3 + s, it = tile / 6, jt = tile % 6;
        bf16x8 ah = ld_lds8(&QH[it * 16 + ln][lq * 8]);
        bf16x8 al = ld_lds8(&QLo[it * 16 + ln][lq * 8]);
        bf16x8 bh = ld_lds8(&KH[jt * 16 + ln][lq * 8]);
        bf16x8 bl = ld_lds8(&KLo[jt * 16 + ln][lq * 8]);
        f32x4 d = (f32x4)0.f;
        d = __builtin_amdgcn_mfma_f32_16x16x32_bf16(al, bh, d, 0, 0, 0);
        d = __builtin_amdgcn_mfma_f32_16x16x32_bf16(ah, bl, d, 0, 0, 0);
        d = __builtin_amdgcn_mfma_f32_16x16x32_bf16(ah, bh, d, 0, 0, 0);
#pragma unroll
        for (int r = 0; r < 4; r++)
            EL[it * 16 + lq * 4 + r][jt * 16 + ln] = d[r];
    }
    __syncthreads();

    {   // ---- softmax: combine with eH stats; write att bf16 ----
        const int pi = t >> 3, sub = t & 7;
        size_t sidx = bP + (size_t)h * kW + w0 + pi;
        float mH = Sm[sidx], sH = Si[sidx];
        float ev[12];
        float mx = mH;
#pragma unroll
        for (int k = 0; k < 12; k++) {
            float e = EL[pi][sub + 8 * k];
            ev[k] = e;
            mx = fmaxf(mx, e);
        }
#pragma unroll
        for (int k = 1; k < 8; k <<= 1) mx = fmaxf(mx, __shfl_xor(mx, k, 8));
        float ss = 0.f;
#pragma unroll
        for (int k = 0; k < 12; k++) { float e = __expf(ev[k] - mx); ev[k] = e; ss += e; }
#pragma unroll
        for (int k = 1; k < 8; k <<= 1) ss += __shfl_xor(ss, k, 8);
        float stot = ss + sH * __expf(mH - mx);
        float inv = 1.0f / stot;
        if (sub == 0) { Sm[sidx] = mx; Si[sidx] = inv; }
#pragma unroll
        for (int k = 0; k < 12; k++)
            attL[pi][sub + 8 * k] = __float2bfloat16(ev[k] * inv);
    }
    __syncthreads();

    // ---- outW = att (32x96) x V (96x256) via MFMA ----
    bf16x8 aF[2][3];
#pragma unroll
    for (int it = 0; it < 2; it++)
#pragma unroll
        for (int j3 = 0; j3 < 3; j3++)
            aF[it][j3] = ld_lds8(&attL[it * 16 + ln][j3 * 32 + lq * 8]);

    f32x4 acc[2][4];
#pragma unroll
    for (int it = 0; it < 2; it++)
#pragma unroll
        for (int c4 = 0; c4 < 4; c4++) acc[it][c4] = (f32x4)0.f;

#pragma unroll
    for (int c4 = 0; c4 < 4; c4++) {
        const int c = (wv * 4 + c4) * 16 + ln;
        const __hip_bfloat16* vr = Vhw + ((size_t)b * kC + c) * kP + (size_t)h * kW;
        bf16x8 bF0 = *(const bf16x8*)&vr[lq * 8];
        bf16x8 bF1 = *(const bf16x8*)&vr[32 + lq * 8];
        bf16x8 bF2 = *(const bf16x8*)&vr[64 + lq * 8];
#pragma unroll
        for (int it = 0; it < 2; it++) {
            acc[it][c4] = __builtin_amdgcn_mfma_f32_16x16x32_bf16(aF[it][0], bF0, acc[it][c4], 0, 0, 0);
            acc[it][c4] = __builtin_amdgcn_mfma_f32_16x16x32_bf16(aF[it][1], bF1, acc[it][c4], 0, 0, 0);
            acc[it][c4] = __builtin_amdgcn_mfma_f32_16x16x32_bf16(aF[it][2], bF2, acc[it][c4], 0, 0, 0);
        }
    }

    // ---- epilogue: gamma*outW + residual -> Zb bf16 ----
    const float gamma = gamma_p[0];
#pragma unroll
    for (int c4 = 0; c4 < 4; c4++) {
        const int c = (wv * 4 + c4) * 16 + ln;
#pragma unroll
        for (int it = 0; it < 2; it++) {
#pragma unroll
            for (int r = 0; r < 4; r++) {
                int i = it * 16 + lq * 4 + r;
                float z = gamma * acc[it][c4][r] + rs[i][c];
                Zb[(bP + (size_t)h * kW + w0 + i) * 512 + s_off + c] = __float2bfloat16(z);
            }
        }
    }
}

// ---------------------------------------------------------------------------
// Kernel C: pass2 (column tiles). grid (3, W, B), block 256.
// Recompute E_H via MFMA, att from stored (m,inv), outH = att x V_col MFMA
// (V staged from pixel-major global), Zb RMW. LDS 74.8 KB.
// ---------------------------------------------------------------------------
__global__ __launch_bounds__(256) void cc_pass2(
    const __hip_bfloat16* __restrict__ Qbh, const __hip_bfloat16* __restrict__ Qbl,
    const __hip_bfloat16* __restrict__ Kbh, const __hip_bfloat16* __restrict__ Kbl,
    const __hip_bfloat16* __restrict__ Vpm,
    const float* __restrict__ gamma_p, __hip_bfloat16* __restrict__ Zb,
    const float* __restrict__ Sm, const float* __restrict__ Si, int s_off)
{
    __shared__ __align__(16) __hip_bfloat16 QH[32][36], QLo[32][36];
    __shared__ __align__(16) __hip_bfloat16 KH[96][36], KLo[96][36];
    __shared__ __align__(16) __hip_bfloat16 VL[96][260];
    __shared__ __align__(16) __hip_bfloat16 attL[32][100];
    const int ht = blockIdx.x, w = blockIdx.y, b = blockIdx.z;
    const int h0 = ht * 32;
    const int t = threadIdx.x;
    const size_t bP = (size_t)b * kP;

    {   // stage Q (rows h0..h0+31 at column w)
        int row = t >> 3, ch = (t & 7) * 4;
        size_t g = (bP + (size_t)(h0 + row) * kW + w) * kCq + ch;
        *(ushort4*)&QH[row][ch]  = *(const ushort4*)&Qbh[g];
        *(ushort4*)&QLo[row][ch] = *(const ushort4*)&Qbl[g];
    }
    for (int idx = t; idx < 768; idx += 256) {   // stage K column (96 rows)
        int row = idx >> 3, ch = (idx & 7) * 4;
        size_t g = (bP + (size_t)row * kW + w) * kCq + ch;
        *(ushort4*)&KH[row][ch]  = *(const ushort4*)&Kbh[g];
        *(ushort4*)&KLo[row][ch] = *(const ushort4*)&Kbl[g];
    }
    for (int idx = t; idx < 96 * 32; idx += 256) {  // stage V column
        int j = idx >> 5, cg = (idx & 31) * 8;
        const ushort4* src = (const ushort4*)&Vpm[(bP + (size_t)j * kW + w) * kC + cg];
        ushort4 v0 = src[0], v1 = src[1];
        *(ushort4*)&VL[j][cg]     = v0;
        *(ushort4*)&VL[j][cg + 4] = v1;
    }
    __syncthreads();

    const int wv = t >> 6, l = t & 63, ln = l & 15, lq = l >> 4;
    // ---- E_H GEMM -> att directly (no fp32 E buffer) ----
#pragma unroll
    for (int s = 0; s < 3; s++) {
        int tile = wv * 3 + s, it = tile / 6, jt = tile % 6;
        bf16x8 ah = ld_lds8(&QH[it * 16 + ln][lq * 8]);
        bf16x8 al = ld_lds8(&QLo[it * 16 + ln][lq * 8]);
        bf16x8 bh = ld_lds8(&KH[jt * 16 + ln][lq * 8]);
        bf16x8 bl = ld_lds8(&KLo[jt * 16 + ln][lq * 8]);
        f32x4 d = (f32x4)0.f;
        d = __builtin_amdgcn_mfma_f32_16x16x32_bf16(al, bh, d, 0, 0, 0);
        d = __builtin_amdgcn_mfma_f32_16x16x32_bf16(ah, bl, d, 0, 0, 0);
        d = __builtin_amdgcn_mfma_f32_16x16x32_bf16(ah, bh, d, 0, 0, 0);
        const int j = jt * 16 + ln;
#pragma unroll
        for (int r = 0; r < 4; r++) {
            int i = it * 16 + lq * 4 + r;
            size_t sidx = bP + (size_t)(h0 + i) * kW + w;
            float m = Sm[sidx], inv = Si[sidx];
            float a = (j == h0 + i) ? 0.f : __expf(d[r] - m) * inv;
            attL[i][j] = __float2bfloat16(a);
        }
    }
    __syncthreads();

    // ---- outH = att (32x96) x V_col (96x256) ----
    bf16x8 aF[2][3];
#pragma unroll
    for (int it = 0; it < 2; it++)
#pragma unroll
        for (int j3 = 0; j3 < 3; j3++)
            aF[it][j3] = ld_lds8(&attL[it * 16 + ln][j3 * 32 + lq * 8]);

    f32x4 acc[2][4];
#pragma unroll
    for (int it = 0; it < 2; it++)
#pragma unroll
        for (int c4 = 0; c4 < 4; c4++) acc[it][c4] = (f32x4)0.f;

#pragma unroll
    for (int c4 = 0; c4 < 4; c4++) {
        const int c = (wv * 4 + c4) * 16 + ln;
#pragma unroll
        for (int j3 = 0; j3 < 3; j3++) {
            union { bf16x8 v; __hip_bfloat16 h[8]; } bF;
#pragma unroll
            for (int jj = 0; jj < 8; jj++)
                bF.h[jj] = VL[j3 * 32 + lq * 8 + jj][c];
#pragma unroll
            for (int it = 0; it < 2; it++)
                acc[it][c4] = __builtin_amdgcn_mfma_f32_16x16x32_bf16(aF[it][j3], bF.v, acc[it][c4], 0, 0, 0);
        }
    }

    // ---- epilogue: Zb RMW ----
    const float gamma = gamma_p[0];
#pragma unroll
    for (int c4 = 0; c4 < 4; c4++) {
        const int c = (wv * 4 + c4) * 16 + ln;
#pragma unroll
        for (int it = 0; it < 2; it++) {
#pragma unroll
            for (int r = 0; r < 4; r++) {
                int i = it * 16 + lq * 4 + r;
                size_t zi = (bP + (size_t)(h0 + i) * kW + w) * 512 + s_off + c;
                float old = __bfloat162float(Zb[zi]);
                Zb[zi] = __float2bfloat16(old + gamma * acc[it][c4][r]);
            }
        }
    }
}

// ---------------------------------------------------------------------------
// Kernel W2: convert Wp [256][512] fp32 -> bf16 (into dead Qb region).
// ---------------------------------------------------------------------------
__global__ __launch_bounds__(256) void wp_convert(
    const float* __restrict__ Wp, __hip_bfloat16* __restrict__ Wpb)
{
    const int i = blockIdx.x * 256 + threadIdx.x;
    Wpb[i] = __float2bfloat16(Wp[i]);
}

// ---------------------------------------------------------------------------
// Kernel D: fused depthwise 3x3 + pointwise 512->256 (bf16 MFMA) + leaky relu.
// (unchanged)
// ---------------------------------------------------------------------------
__global__ __launch_bounds__(256) void dwpw(
    const __hip_bfloat16* __restrict__ Zb,
    const float* __restrict__ Wdw, const float* __restrict__ bd,
    const __hip_bfloat16* __restrict__ Wpb, const float* __restrict__ bp,
    float* __restrict__ out)
{
    __shared__ __align__(16) char smem[33792];
    __hip_bfloat16 (*zs)[520] = (__hip_bfloat16 (*)[520])smem;

    const int wt = blockIdx.x, h = blockIdx.y, b = blockIdx.z;
    const int w0 = wt * 32;
    const int t = threadIdx.x;
    const size_t bP = (size_t)b * kP;

    {
        float wd0[9], wd1[9];
#pragma unroll
        for (int k = 0; k < 9; k++) {
            wd0[k] = Wdw[(size_t)(2 * t) * 9 + k];
            wd1[k] = Wdw[(size_t)(2 * t + 1) * 9 + k];
        }
        const float b0 = bd[2 * t], b1 = bd[2 * t + 1];
        const __hip_bfloat162* __restrict__ Zp =
            (const __hip_bfloat162*)Zb + bP * 256 + t;
        const bool rvm = (h > 0), rvp = (h < kH - 1);

#pragma unroll
        for (int j0 = 0; j0 < 32; j0 += 8) {
            float2 wf[10][3];
#pragma unroll
            for (int col = 0; col < 10; col++) {
                const int ww = w0 + j0 - 1 + col;
                const bool cv = (ww >= 0) && (ww < kW);
#pragma unroll
                for (int r = 0; r < 3; r++) {
                    const bool v = cv && (r == 1 || (r == 0 ? rvm : rvp));
                    __hip_bfloat162 z2;
                    z2.x = __ushort_as_bfloat16(0);
                    z2.y = __ushort_as_bfloat16(0);
                    if (v) z2 = Zp[(size_t)((h + r - 1) * kW + ww) * 256];
                    wf[col][r] = __bfloat1622float2(z2);
                }
            }
#pragma unroll
            for (int j = 0; j < 8; j++) {
                float a0 = b0, a1 = b1;
#pragma unroll
                for (int r = 0; r < 3; r++) {
#pragma unroll
                    for (int dw = 0; dw < 3; dw++) {
                        const float2 z = wf[j + dw][r];
                        const int k = r * 3 + dw;
                        a0 += wd0[k] * z.x;
                        a1 += wd1[k] * z.y;
                    }
                }
                __hip_bfloat162 pz;
                pz.x = __float2bfloat16(a0);
                pz.y = __float2bfloat16(a1);
                ((__hip_bfloat162*)&zs[j0 + j][0])[t] = pz;
            }
        }
    }
    __syncthreads();

    const int l = t & 63, wv = t >> 6;
    const int lo16 = l & 15, q = l >> 4;

    f32x4 acc[2][4];
#pragma unroll
    for (int mt = 0; mt < 2; mt++)
#pragma unroll
        for (int nt = 0; nt < 4; nt++) acc[mt][nt] = (f32x4)0.f;

    const bf16x8* __restrict__ Bb[4];
#pragma unroll
    for (int nt = 0; nt < 4; nt++)
        Bb[nt] = (const bf16x8*)(Wpb + (size_t)(wv * 64 + nt * 16 + lo16) * 512);

    for (int kc = 0; kc < 16; kc++) {
        bf16x8 a0 = *(const bf16x8*)&zs[lo16][kc * 32 + q * 8];
        bf16x8 a1 = *(const bf16x8*)&zs[16 + lo16][kc * 32 + q * 8];
#pragma unroll
        for (int nt = 0; nt < 4; nt++) {
            bf16x8 bf = Bb[nt][kc * 4 + q];
            acc[0][nt] = __builtin_amdgcn_mfma_f32_16x16x32_bf16(a0, bf, acc[0][nt], 0, 0, 0);
            acc[1][nt] = __builtin_amdgcn_mfma_f32_16x16x32_bf16(a1, bf, acc[1][nt], 0, 0, 0);
        }
    }
    __syncthreads();

    float* os = (float*)smem + (size_t)wv * 64 * 33;
#pragma unroll
    for (int nt = 0; nt < 4; nt++) {
        const int ol = nt * 16 + lo16;
        const float bias = bp[wv * 64 + ol];
#pragma unroll
        for (int mt = 0; mt < 2; mt++) {
#pragma unroll
            for (int r = 0; r < 4; r++) {
                float v = acc[mt][nt][r] + bias;
                v = v > 0.f ? v : 0.01f * v;
                os[ol * 33 + mt * 16 + q * 4 + r] = v;
            }
        }
    }
    __syncthreads();
    const int px = l & 31, oh = l >> 5;
    for (int j = 0; j < 32; j++) {
        const int ol = j * 2 + oh;
        out[((size_t)b * 256 + wv * 64 + ol) * kP + (size_t)h * kW + w0 + px] =
            os[ol * 33 + px];
    }
}

// ---------------------------------------------------------------------------
extern "C" void kernel_launch(void* const* d_in, const int* in_sizes, int n_in,
                              void* d_out, int out_size, void* d_ws, size_t ws_size,
                              hipStream_t stream)
{
    const float* x   = (const float*)d_in[0];
    const float* y   = (const float*)d_in[1];
    const float* Wq  = (const float*)d_in[2];
    const float* bq  = (const float*)d_in[3];
    const float* Wk  = (const float*)d_in[4];
    const float* bk  = (const float*)d_in[5];
    const float* Wv  = (const float*)d_in[6];
    const float* bv  = (const float*)d_in[7];
    const float* g1  = (const float*)d_in[8];
    const float* g2  = (const float*)d_in[9];
    const float* Wdw = (const float*)d_in[10];
    const float* bd  = (const float*)d_in[11];
    const float* Wp  = (const float*)d_in[12];
    const float* bp  = (const float*)d_in[13];
    float* out = (float*)d_out;

    // Workspace layout (94,961,664 B total — unchanged):
    //   Zb       : bf16 [8][9216][512]      = 75,497,472
    //   Qb hi/lo : bf16 2x[8][9216][32]     =  9,437,184
    //   Kb hi/lo : bf16 2x[8][9216][32]     =  9,437,184
    //   Sm, Si   : fp32 [8][9216]           =    294,912 each
    // V (bf16, two layouts) lives in d_out until dwpw:
    //   Vpm [8][9216][256] @ +0, Vhw [8][256][9216] @ +37,748,736.
    // Wqkb/Wvb alias the (dead at qkv time) Sm region; Wpb aliases Qb region.
    char* wsb = (char*)d_ws;
    __hip_bfloat16* Zb  = (__hip_bfloat16*)wsb;
    __hip_bfloat16* Qbh = (__hip_bfloat16*)(wsb + 75497472);
    __hip_bfloat16* Qbl = Qbh + 2359296;
    __hip_bfloat16* Kbh = (__hip_bfloat16*)(wsb + 84934656);
    __hip_bfloat16* Kbl = Kbh + 2359296;
    float* Sm = (float*)(wsb + 94371840);
    float* Si = (float*)(wsb + 94666752);
    __hip_bfloat16* Wqkb = (__hip_bfloat16*)Sm;
    __hip_bfloat16* Wvb  = ((__hip_bfloat16*)Sm) + 16384;
    __hip_bfloat16* Wpb  = (__hip_bfloat16*)(wsb + 75497472);  // dead Qb region
    __hip_bfloat16* Vpm  = (__hip_bfloat16*)d_out;
    __hip_bfloat16* Vhw  = Vpm + 18874368;

    // stream 1: q,k from x; v from y; residual x; channels [0,256)
    hipLaunchKernelGGL(w_convert, dim3(320), dim3(256), 0, stream,
                       Wq, Wk, Wv, Wqkb, Wvb);
    hipLaunchKernelGGL(qkv_mfma, dim3(kP / 64, kB), dim3(256), 0, stream,
                       x, y, Wqkb, Wvb, bq, bk, bv, Qbh, Qbl, Kbh, Kbl, Vpm, Vhw);
    hipLaunchKernelGGL(cc_stats, dim3(kW, kB), dim3(256), 0, stream,
                       Qbh, Qbl, Kbh, Kbl, Sm, Si);
    hipLaunchKernelGGL(cc_pass1, dim3(kW / 32, kH, kB), dim3(256), 0, stream,
                       Qbh, Qbl, Kbh, Kbl, Vhw, x, g1, Zb, Sm, Si, 0);
    hipLaunchKernelGGL(cc_pass2, dim3(kH / 32, kW, kB), dim3(256), 0, stream,
                       Qbh, Qbl, Kbh, Kbl, Vpm, g1, Zb, Sm, Si, 0);
    // stream 2: q,k from y; v from x; residual y; channels [256,512)
    hipLaunchKernelGGL(w_convert, dim3(320), dim3(256), 0, stream,
                       Wq, Wk, Wv, Wqkb, Wvb);
    hipLaunchKernelGGL(qkv_mfma, dim3(kP / 64, kB), dim3(256), 0, stream,
                       y, x, Wqkb, Wvb, bq, bk, bv, Qbh, Qbl, Kbh, Kbl, Vpm, Vhw);
    hipLaunchKernelGGL(cc_stats, dim3(kW, kB), dim3(256), 0, stream,
                       Qbh, Qbl, Kbh, Kbl, Sm, Si);
    hipLaunchKernelGGL(cc_pass1, dim3(kW / 32, kH, kB), dim3(256), 0, stream,
                       Qbh, Qbl, Kbh, Kbl, Vhw, y, g2, Zb, Sm, Si, 256);
    hipLaunchKernelGGL(cc_pass2, dim3(kH / 32, kW, kB), dim3(256), 0, stream,
                       Qbh, Qbl, Kbh, Kbl, Vpm, g2, Zb, Sm, Si, 256);
    // convert Wp to bf16 (Qb region dead now)
    hipLaunchKernelGGL(wp_convert, dim3(512), dim3(256), 0, stream, Wp, Wpb);
    // fused depthwise + pointwise MFMA + leaky relu (overwrites d_out)
    hipLaunchKernelGGL(dwpw, dim3(kW / 32, kH, kB), dim3(256), 0, stream,
                       Zb, Wdw, bd, Wpb, bp, out);
}